// Round 3
// baseline (3072.705 us; speedup 1.0000x reference)
//
#include <hip/hip_runtime.h>
#include <stdint.h>

typedef unsigned short u16;
typedef unsigned long long u64;

#define N_ROWS 32768
#define DIM 256
#define K_CODES 8192
#define TAU 0.3f

// workspace offsets (bytes)
#define A_OFF    0ull            // 32768*256*2 = 16777216
#define B_OFF    16777216ull     // 8192*256*2  = 4194304
#define CN_OFF   20971520ull     // 8192*4
#define PART_OFF 21004288ull     // 32768*4*16 = 2097152
#define IDX_OFF  23101440ull     // 32768*4
#define HIST_OFF 23232512ull     // 8192*4
#define CNT_OFF  23265280ull     // 16 (memset together with hist)
#define FLAG_OFF 23265296ull     // 32768*4
#define LOSS_OFF 23396368ull     // 8192*4

// output offsets (float elements)
#define OUT_Q 0
#define OUT_T 8388608
#define OUT_S 8421376

#define BM 128
#define BN 128
#define BK 64
#define JSPLIT 4

typedef _Float16 half8 __attribute__((ext_vector_type(8)));
typedef float floatx4 __attribute__((ext_vector_type(4)));

struct __align__(16) u64x2 { u64 a, b; };

__device__ __forceinline__ void gload_lds16(const void* g, void* l) {
    __builtin_amdgcn_global_load_lds(
        (const __attribute__((address_space(1))) void*)g,
        (__attribute__((address_space(3))) void*)l,
        16, 0, 0);
}

__device__ __forceinline__ unsigned sortable(float v) {
    unsigned u = __float_as_uint(v);
    return (u & 0x80000000u) ? ~u : (u | 0x80000000u);
}
__device__ __forceinline__ float unsortable(unsigned u) {
    return (u & 0x80000000u) ? __uint_as_float(u & 0x7fffffffu) : __uint_as_float(~u);
}
__device__ __forceinline__ u64 shfl64x(u64 v, int m) {
    return ((u64)(unsigned)__shfl_xor((int)(v >> 32), m, 64) << 32) |
           (unsigned)__shfl_xor((int)(v & 0xffffffffu), m, 64);
}
__device__ __forceinline__ u64 u64min(u64 a, u64 b) { return a < b ? a : b; }
__device__ __forceinline__ u64 u64max(u64 a, u64 b) { return a > b ? a : b; }

// fp32 -> f16 (hi) cast for inputs and codebook; fused ||c||^2.
__global__ void prep(const float* __restrict__ inp, const float* __restrict__ cb,
                     u16* __restrict__ A, u16* __restrict__ B, float* __restrict__ cn) {
    int g = blockIdx.x * 256 + threadIdx.x;       // 40960 rows * 32 threads
    int row = g >> 5;
    int kc = (g & 31) << 3;
    bool isA = row < N_ROWS;
    const float* src = isA ? inp + (size_t)row * DIM + kc
                           : cb + (size_t)(row - N_ROWS) * DIM + kc;
    u16* dst = isA ? A + (size_t)row * DIM + kc
                   : B + (size_t)(row - N_ROWS) * DIM + kc;
    float4 x0 = *(const float4*)(src);
    float4 x1 = *(const float4*)(src + 4);
    float xs[8] = {x0.x, x0.y, x0.z, x0.w, x1.x, x1.y, x1.z, x1.w};
    half8 hv;
    float s = 0.f;
#pragma unroll
    for (int i = 0; i < 8; ++i) {
        hv[i] = (_Float16)xs[i];
        s = fmaf(xs[i], xs[i], s);
    }
    *(half8*)(dst) = hv;
    if (!isA) {
#pragma unroll
        for (int m = 1; m <= 16; m <<= 1) s += __shfl_xor(s, m, 64);
        if ((g & 31) == 0) cn[row - N_ROWS] = s;
    }
}

// pass 1: hi*hi K=256 f16 MFMA GEMM + per-row top-2 (packed sortable-dist|idx)
__launch_bounds__(256, 4)
__global__ void vq_pass1(const u16* __restrict__ A, const u16* __restrict__ B,
                         const float* __restrict__ cn, u64x2* __restrict__ part) {
    __shared__ __align__(16) _Float16 lsA[BM * BK];
    __shared__ __align__(16) _Float16 lsB[BN * BK];
    __shared__ u64 t1buf[BM], t2buf[BM];

    const int tid = threadIdx.x;
    const int lane = tid & 63;
    const int w = tid >> 6;
    const int wm = w >> 1, wn = w & 1;
    const int l15 = lane & 15;
    const int quad = lane >> 4;
    const int xm = l15 & 7;
    const int rowBase = blockIdx.x * BM;
    const int jBase = blockIdx.y * (K_CODES / JSPLIT);

    u64 m1[16], m2[16];
#pragma unroll
    for (int i = 0; i < 16; ++i) { m1[i] = ~0ull; m2[i] = ~0ull; }

    const int str = tid >> 3;
    const int sk16 = tid & 7;

    for (int jc = 0; jc < (K_CODES / JSPLIT) / BN; ++jc) {
        const int colBase = jBase + jc * BN;
        floatx4 acc[4][4];
#pragma unroll
        for (int mi = 0; mi < 4; ++mi)
#pragma unroll
            for (int ni = 0; ni < 4; ++ni)
                acc[mi][ni] = (floatx4){0.f, 0.f, 0.f, 0.f};

#pragma unroll 1
        for (int kk = 0; kk < DIM; kk += BK) {
#pragma unroll
            for (int it = 0; it < 4; ++it) {
                int r = it * 32 + str;
                int cdat = sk16 ^ (r & 7);           // XOR-swizzled source chunk
                int ch = it * 256 + tid;
                gload_lds16(A + (size_t)(rowBase + r) * DIM + kk + cdat * 8,
                            (char*)lsA + ch * 16);
                gload_lds16(B + (size_t)(colBase + r) * DIM + kk + cdat * 8,
                            (char*)lsB + ch * 16);
            }
            __syncthreads();
#pragma unroll
            for (int s = 0; s < 2; ++s) {
                const int koff = ((s * 4 + quad) ^ xm) * 8;
                half8 af[4], bf[4];
#pragma unroll
                for (int mi = 0; mi < 4; ++mi)
                    af[mi] = *(const half8*)(lsA + (wm * 64 + mi * 16 + l15) * BK + koff);
#pragma unroll
                for (int ni = 0; ni < 4; ++ni)
                    bf[ni] = *(const half8*)(lsB + (wn * 64 + ni * 16 + l15) * BK + koff);
#pragma unroll
                for (int mi = 0; mi < 4; ++mi)
#pragma unroll
                    for (int ni = 0; ni < 4; ++ni)
                        acc[mi][ni] = __builtin_amdgcn_mfma_f32_16x16x32_f16(
                            af[mi], bf[ni], acc[mi][ni], 0, 0, 0);
            }
            __syncthreads();
        }

        // top-2 insert; C/D layout col=lane&15, row=quad*4+reg
#pragma unroll
        for (int ni = 0; ni < 4; ++ni) {
            int j = colBase + wn * 64 + ni * 16 + l15;
            float cnj = cn[j];
#pragma unroll
            for (int mi = 0; mi < 4; ++mi) {
#pragma unroll
                for (int r = 0; r < 4; ++r) {
                    float val = cnj - 2.0f * acc[mi][ni][r];
                    u64 pk = ((u64)sortable(val) << 32) | (unsigned)j;
                    int tr = mi * 4 + r;
                    if (pk < m2[tr]) {
                        if (pk < m1[tr]) { m2[tr] = m1[tr]; m1[tr] = pk; }
                        else m2[tr] = pk;
                    }
                }
            }
        }
    }

    // merge top-2 across the 16 lanes sharing each row
#pragma unroll
    for (int m = 1; m <= 8; m <<= 1)
#pragma unroll
        for (int tr = 0; tr < 16; ++tr) {
            u64 o1 = shfl64x(m1[tr], m), o2 = shfl64x(m2[tr], m);
            u64 n1 = u64min(m1[tr], o1);
            u64 n2 = u64min(u64max(m1[tr], o1), u64min(m2[tr], o2));
            m1[tr] = n1; m2[tr] = n2;
        }

    // merge the two column-half waves (wn=0 publishes, wn=1 merges & writes)
    if (wn == 0 && l15 == 0) {
#pragma unroll
        for (int tr = 0; tr < 16; ++tr) {
            int rl = wm * 64 + (tr >> 2) * 16 + quad * 4 + (tr & 3);
            t1buf[rl] = m1[tr]; t2buf[rl] = m2[tr];
        }
    }
    __syncthreads();
    if (wn == 1 && l15 == 0) {
#pragma unroll
        for (int tr = 0; tr < 16; ++tr) {
            int rl = wm * 64 + (tr >> 2) * 16 + quad * 4 + (tr & 3);
            u64 o1 = t1buf[rl], o2 = t2buf[rl];
            u64 n1 = u64min(m1[tr], o1);
            u64 n2 = u64min(u64max(m1[tr], o1), u64min(m2[tr], o2));
            part[(size_t)(rowBase + rl) * JSPLIT + blockIdx.y] = (u64x2){n1, n2};
        }
    }
}

// merge JSPLIT partial top-2s; emit idx + flag near-ties for exact recompute
__global__ void vq_merge(const u64x2* __restrict__ part, unsigned* __restrict__ idx32,
                         int* __restrict__ flaglist, int* __restrict__ cnt) {
    int row = blockIdx.x * 256 + threadIdx.x;
    u64 m1 = ~0ull, m2 = ~0ull;
#pragma unroll
    for (int y = 0; y < JSPLIT; ++y) {
        u64x2 p = part[(size_t)row * JSPLIT + y];
        u64 n1 = u64min(m1, p.a);
        u64 n2 = u64min(u64max(m1, p.a), u64min(m2, p.b));
        m1 = n1; m2 = n2;
    }
    idx32[row] = (unsigned)(m1 & 0xffffffffu);
    float f1 = unsortable((unsigned)(m1 >> 32));
    float f2 = unsortable((unsigned)(m2 >> 32));
    if (f2 - f1 < TAU) {
        int p = atomicAdd(cnt, 1);
        flaglist[p] = row;
    }
}

// exact fp32 full-scan argmin for flagged rows. One wave per row; x in LDS
// (broadcast reads), codes streamed from global.
__global__ void vq_recompute(const float* __restrict__ inp, const float* __restrict__ cb,
                             const float* __restrict__ cn, const int* __restrict__ flaglist,
                             const int* __restrict__ cnt, unsigned* __restrict__ idx32) {
    __shared__ float ls[4][DIM];
    const int w = threadIdx.x >> 6, lane = threadIdx.x & 63;
    const int n = *cnt;
    for (int base = blockIdx.x * 4; base < n; base += 256 * 4) {
        int li = base + w;
        if (li >= n) continue;
        int row = flaglist[li];
        float4 xv = ((const float4*)(inp + (size_t)row * DIM))[lane];
        *(float4*)&ls[w][lane * 4] = xv;
        u64 best = ~0ull;
        for (int m = 0; m < K_CODES / 64; ++m) {
            int j = lane + 64 * m;
            const float4* cj = (const float4*)(cb + (size_t)j * DIM);
            float ax = 0.f, ay = 0.f, az = 0.f, aw = 0.f;
#pragma unroll 8
            for (int d = 0; d < DIM / 4; ++d) {
                float4 x = *(const float4*)&ls[w][d * 4];   // same addr all lanes: broadcast
                float4 c = cj[d];
                ax = fmaf(x.x, c.x, ax); ay = fmaf(x.y, c.y, ay);
                az = fmaf(x.z, c.z, az); aw = fmaf(x.w, c.w, aw);
            }
            float dist = cn[j] - 2.0f * ((ax + ay) + (az + aw));
            u64 pk = ((u64)sortable(dist) << 32) | (unsigned)j;
            best = u64min(best, pk);
        }
#pragma unroll
        for (int mm = 1; mm <= 32; mm <<= 1) best = u64min(best, shfl64x(best, mm));
        if (lane == 0) idx32[row] = (unsigned)(best & 0xffffffffu);
    }
}

// gather codebook rows, write quantized + tokens, per-block loss partial, histogram
__global__ void vq_gather(const float* __restrict__ inp, const float* __restrict__ cb,
                          const unsigned* __restrict__ idx32, float* __restrict__ out,
                          float* __restrict__ losspart, unsigned int* __restrict__ hist) {
    __shared__ float red[4];
    int w = threadIdx.x >> 6, lane = threadIdx.x & 63;
    int i = blockIdx.x * 4 + w;
    unsigned idx = idx32[i];
    float4 c = ((const float4*)(cb + (size_t)idx * DIM))[lane];
    float4 x = ((const float4*)(inp + (size_t)i * DIM))[lane];
    ((float4*)(out + OUT_Q))[(size_t)i * 64 + lane] = c;
    float dx = c.x - x.x, dy = c.y - x.y, dz = c.z - x.z, dw = c.w - x.w;
    float s = dx * dx + dy * dy + dz * dz + dw * dw;
#pragma unroll
    for (int m = 32; m; m >>= 1) s += __shfl_xor(s, m, 64);
    if (lane == 0) {
        out[OUT_T + i] = (float)idx;
        red[w] = s;
        atomicAdd(&hist[idx], 1u);
    }
    __syncthreads();
    if (threadIdx.x == 0)
        losspart[blockIdx.x] = red[0] + red[1] + red[2] + red[3];
}

__global__ void vq_finalize(const unsigned int* __restrict__ hist,
                            const float* __restrict__ losspart, float* __restrict__ out) {
    __shared__ float redp[256], redl[256];
    int tid = threadIdx.x;
    float sp = 0.f, sl = 0.f;
    for (int k = tid; k < K_CODES; k += 256) {
        float p = (float)hist[k] * (1.0f / (float)N_ROWS);
        sp += p * logf(p + 1e-10f);
        sl += losspart[k];
    }
    redp[tid] = sp; redl[tid] = sl;
    __syncthreads();
    for (int st = 128; st; st >>= 1) {
        if (tid < st) { redp[tid] += redp[tid + st]; redl[tid] += redl[tid + st]; }
        __syncthreads();
    }
    if (tid == 0) {
        float perp = expf(-redp[0]);
        float e = redl[0] / 8388608.0f;      // mean((q - x)^2)
        out[OUT_S + 0] = 1.25f * e;          // vq_loss
        out[OUT_S + 1] = 0.25f * e;          // commitment_loss
        out[OUT_S + 2] = e;                  // codebook_loss
        out[OUT_S + 3] = perp;               // perplexity
    }
}

extern "C" void kernel_launch(void* const* d_in, const int* in_sizes, int n_in,
                              void* d_out, int out_size, void* d_ws, size_t ws_size,
                              hipStream_t stream) {
    const float* inp = (const float*)d_in[0];
    const float* cb = (const float*)d_in[1];
    float* out = (float*)d_out;
    char* ws = (char*)d_ws;
    u16* A = (u16*)(ws + A_OFF);
    u16* B = (u16*)(ws + B_OFF);
    float* cn = (float*)(ws + CN_OFF);
    u64x2* part = (u64x2*)(ws + PART_OFF);
    unsigned* idx32 = (unsigned*)(ws + IDX_OFF);
    unsigned int* hist = (unsigned int*)(ws + HIST_OFF);
    int* cnt = (int*)(ws + CNT_OFF);
    int* flaglist = (int*)(ws + FLAG_OFF);
    float* losspart = (float*)(ws + LOSS_OFF);

    hipMemsetAsync(hist, 0, K_CODES * 4 + 16, stream);   // hist + cnt

    prep<<<5120, 256, 0, stream>>>(inp, cb, A, B, cn);
    vq_pass1<<<dim3(N_ROWS / BM, JSPLIT), 256, 0, stream>>>(A, B, cn, part);
    vq_merge<<<N_ROWS / 256, 256, 0, stream>>>(part, idx32, flaglist, cnt);
    vq_recompute<<<256, 256, 0, stream>>>(inp, cb, cn, flaglist, cnt, idx32);
    vq_gather<<<N_ROWS / 4, 256, 0, stream>>>(inp, cb, idx32, out, losspart, hist);
    vq_finalize<<<1, 256, 0, stream>>>(hist, losspart, out);
}

// Round 4
// 1522.856 us; speedup vs baseline: 2.0177x; 2.0177x over previous
//
#include <hip/hip_runtime.h>
#include <stdint.h>

typedef unsigned short u16;
typedef unsigned long long u64;

#define N_ROWS 32768
#define DIM 256
#define K_CODES 8192
#define TAU 0.3f

// workspace offsets (bytes)
#define A_OFF    0ull            // 32768*256*2 = 16777216
#define B_OFF    16777216ull     // 8192*256*2  = 4194304
#define CN_OFF   20971520ull     // 8192*4
#define PART_OFF 21004288ull     // 32768*4*16 = 2097152
#define IDX_OFF  23101440ull     // 32768*4
#define HIST_OFF 23232512ull     // 8192*4
#define CNT_OFF  23265280ull     // 16 (memset together with hist)
#define FLAG_OFF 23265296ull     // 32768*4
#define LOSS_OFF 23396368ull     // 8192*4

// output offsets (float elements)
#define OUT_Q 0
#define OUT_T 8388608
#define OUT_S 8421376

#define BM 128
#define BN 128
#define BK 64
#define JSPLIT 4

typedef _Float16 half8 __attribute__((ext_vector_type(8)));
typedef float floatx4 __attribute__((ext_vector_type(4)));

struct __align__(16) u64x2 { u64 a, b; };

__device__ __forceinline__ void gload_lds16(const void* g, void* l) {
    __builtin_amdgcn_global_load_lds(
        (const __attribute__((address_space(1))) void*)g,
        (__attribute__((address_space(3))) void*)l,
        16, 0, 0);
}

__device__ __forceinline__ unsigned sortable(float v) {
    unsigned u = __float_as_uint(v);
    return (u & 0x80000000u) ? ~u : (u | 0x80000000u);
}
__device__ __forceinline__ float unsortable(unsigned u) {
    return (u & 0x80000000u) ? __uint_as_float(u & 0x7fffffffu) : __uint_as_float(~u);
}
__device__ __forceinline__ u64 shfl64x(u64 v, int m) {
    return ((u64)(unsigned)__shfl_xor((int)(v >> 32), m, 64) << 32) |
           (unsigned)__shfl_xor((int)(v & 0xffffffffu), m, 64);
}
__device__ __forceinline__ u64 u64min(u64 a, u64 b) { return a < b ? a : b; }
__device__ __forceinline__ u64 u64max(u64 a, u64 b) { return a > b ? a : b; }

// fp32 -> f16 (hi) cast for inputs and codebook; fused ||c||^2.
__global__ void prep(const float* __restrict__ inp, const float* __restrict__ cb,
                     u16* __restrict__ A, u16* __restrict__ B, float* __restrict__ cn) {
    int g = blockIdx.x * 256 + threadIdx.x;       // 40960 rows * 32 threads
    int row = g >> 5;
    int kc = (g & 31) << 3;
    bool isA = row < N_ROWS;
    const float* src = isA ? inp + (size_t)row * DIM + kc
                           : cb + (size_t)(row - N_ROWS) * DIM + kc;
    u16* dst = isA ? A + (size_t)row * DIM + kc
                   : B + (size_t)(row - N_ROWS) * DIM + kc;
    float4 x0 = *(const float4*)(src);
    float4 x1 = *(const float4*)(src + 4);
    float xs[8] = {x0.x, x0.y, x0.z, x0.w, x1.x, x1.y, x1.z, x1.w};
    half8 hv;
    float s = 0.f;
#pragma unroll
    for (int i = 0; i < 8; ++i) {
        hv[i] = (_Float16)xs[i];
        s = fmaf(xs[i], xs[i], s);
    }
    *(half8*)(dst) = hv;
    if (!isA) {
#pragma unroll
        for (int m = 1; m <= 16; m <<= 1) s += __shfl_xor(s, m, 64);
        if ((g & 31) == 0) cn[row - N_ROWS] = s;
    }
}

// pass 1: hi*hi K=256 f16 MFMA GEMM + per-row top-2 (packed sortable-dist|idx)
__launch_bounds__(256, 4)
__global__ void vq_pass1(const u16* __restrict__ A, const u16* __restrict__ B,
                         const float* __restrict__ cn, u64x2* __restrict__ part) {
    __shared__ __align__(16) _Float16 lsA[BM * BK];
    __shared__ __align__(16) _Float16 lsB[BN * BK];
    __shared__ u64 t1buf[BM], t2buf[BM];

    const int tid = threadIdx.x;
    const int lane = tid & 63;
    const int w = tid >> 6;
    const int wm = w >> 1, wn = w & 1;
    const int l15 = lane & 15;
    const int quad = lane >> 4;
    const int xm = l15 & 7;
    const int rowBase = blockIdx.x * BM;
    const int jBase = blockIdx.y * (K_CODES / JSPLIT);

    u64 m1[16], m2[16];
#pragma unroll
    for (int i = 0; i < 16; ++i) { m1[i] = ~0ull; m2[i] = ~0ull; }

    const int str = tid >> 3;
    const int sk16 = tid & 7;

    for (int jc = 0; jc < (K_CODES / JSPLIT) / BN; ++jc) {
        const int colBase = jBase + jc * BN;
        floatx4 acc[4][4];
#pragma unroll
        for (int mi = 0; mi < 4; ++mi)
#pragma unroll
            for (int ni = 0; ni < 4; ++ni)
                acc[mi][ni] = (floatx4){0.f, 0.f, 0.f, 0.f};

#pragma unroll 1
        for (int kk = 0; kk < DIM; kk += BK) {
#pragma unroll
            for (int it = 0; it < 4; ++it) {
                int r = it * 32 + str;
                int cdat = sk16 ^ (r & 7);           // XOR-swizzled source chunk
                int ch = it * 256 + tid;
                gload_lds16(A + (size_t)(rowBase + r) * DIM + kk + cdat * 8,
                            (char*)lsA + ch * 16);
                gload_lds16(B + (size_t)(colBase + r) * DIM + kk + cdat * 8,
                            (char*)lsB + ch * 16);
            }
            __syncthreads();
#pragma unroll
            for (int s = 0; s < 2; ++s) {
                const int koff = ((s * 4 + quad) ^ xm) * 8;
                half8 af[4], bf[4];
#pragma unroll
                for (int mi = 0; mi < 4; ++mi)
                    af[mi] = *(const half8*)(lsA + (wm * 64 + mi * 16 + l15) * BK + koff);
#pragma unroll
                for (int ni = 0; ni < 4; ++ni)
                    bf[ni] = *(const half8*)(lsB + (wn * 64 + ni * 16 + l15) * BK + koff);
#pragma unroll
                for (int mi = 0; mi < 4; ++mi)
#pragma unroll
                    for (int ni = 0; ni < 4; ++ni)
                        acc[mi][ni] = __builtin_amdgcn_mfma_f32_16x16x32_f16(
                            af[mi], bf[ni], acc[mi][ni], 0, 0, 0);
            }
            __syncthreads();
        }

        // top-2 insert; C/D layout col=lane&15, row=quad*4+reg
#pragma unroll
        for (int ni = 0; ni < 4; ++ni) {
            int j = colBase + wn * 64 + ni * 16 + l15;
            float cnj = cn[j];
#pragma unroll
            for (int mi = 0; mi < 4; ++mi) {
#pragma unroll
                for (int r = 0; r < 4; ++r) {
                    float val = cnj - 2.0f * acc[mi][ni][r];
                    u64 pk = ((u64)sortable(val) << 32) | (unsigned)j;
                    int tr = mi * 4 + r;
                    if (pk < m2[tr]) {
                        if (pk < m1[tr]) { m2[tr] = m1[tr]; m1[tr] = pk; }
                        else m2[tr] = pk;
                    }
                }
            }
        }
    }

    // merge top-2 across the 16 lanes sharing each row
#pragma unroll
    for (int m = 1; m <= 8; m <<= 1)
#pragma unroll
        for (int tr = 0; tr < 16; ++tr) {
            u64 o1 = shfl64x(m1[tr], m), o2 = shfl64x(m2[tr], m);
            u64 n1 = u64min(m1[tr], o1);
            u64 n2 = u64min(u64max(m1[tr], o1), u64min(m2[tr], o2));
            m1[tr] = n1; m2[tr] = n2;
        }

    // merge the two column-half waves (wn=0 publishes, wn=1 merges & writes)
    if (wn == 0 && l15 == 0) {
#pragma unroll
        for (int tr = 0; tr < 16; ++tr) {
            int rl = wm * 64 + (tr >> 2) * 16 + quad * 4 + (tr & 3);
            t1buf[rl] = m1[tr]; t2buf[rl] = m2[tr];
        }
    }
    __syncthreads();
    if (wn == 1 && l15 == 0) {
#pragma unroll
        for (int tr = 0; tr < 16; ++tr) {
            int rl = wm * 64 + (tr >> 2) * 16 + quad * 4 + (tr & 3);
            u64 o1 = t1buf[rl], o2 = t2buf[rl];
            u64 n1 = u64min(m1[tr], o1);
            u64 n2 = u64min(u64max(m1[tr], o1), u64min(m2[tr], o2));
            part[(size_t)(rowBase + rl) * JSPLIT + blockIdx.y] = (u64x2){n1, n2};
        }
    }
}

// merge JSPLIT partial top-2s; emit idx + flag near-ties for exact recompute
__global__ void vq_merge(const u64x2* __restrict__ part, unsigned* __restrict__ idx32,
                         int* __restrict__ flaglist, int* __restrict__ cnt) {
    int row = blockIdx.x * 256 + threadIdx.x;
    u64 m1 = ~0ull, m2 = ~0ull;
#pragma unroll
    for (int y = 0; y < JSPLIT; ++y) {
        u64x2 p = part[(size_t)row * JSPLIT + y];
        u64 n1 = u64min(m1, p.a);
        u64 n2 = u64min(u64max(m1, p.a), u64min(m2, p.b));
        m1 = n1; m2 = n2;
    }
    idx32[row] = (unsigned)(m1 & 0xffffffffu);
    float f1 = unsortable((unsigned)(m1 >> 32));
    float f2 = unsortable((unsigned)(m2 >> 32));
    if (f2 - f1 < TAU) {
        int p = atomicAdd(cnt, 1);
        flaglist[p] = row;
    }
}

// exact fp32 full-scan argmin for flagged rows.
// One BLOCK per row; 4 waves split the 8192 codes; lane = (c4, d16):
// 4 codes x 16 dim-lanes per load -> 256B-coalesced segments, 8 loads in flight.
__global__ void vq_recompute(const float* __restrict__ inp, const float* __restrict__ cb,
                             const float* __restrict__ cn, const int* __restrict__ flaglist,
                             const int* __restrict__ cnt, unsigned* __restrict__ idx32) {
    __shared__ float xs[DIM];
    __shared__ u64 wbest[4];
    const int tid = threadIdx.x;
    const int w = tid >> 6, lane = tid & 63;
    const int c4 = lane >> 4;      // code within group of 4
    const int d16 = lane & 15;     // dim-lane
    const int n = *cnt;
    for (int li = blockIdx.x; li < n; li += 1024) {
        int row = flaglist[li];
        if (tid < 64)
            ((float4*)xs)[tid] = ((const float4*)(inp + (size_t)row * DIM))[tid];
        __syncthreads();
        float4 xr[4];
#pragma unroll
        for (int p = 0; p < 4; ++p) xr[p] = *(const float4*)&xs[p * 64 + d16 * 4];

        u64 best = ~0ull;
        // wave w covers codes [w*2048, (w+1)*2048), 8 codes (2 groups) per iter
        for (int jb = w * 2048; jb < (w + 1) * 2048; jb += 8) {
            int j0 = jb + c4, j1 = jb + 4 + c4;
            float s0 = 0.f, s1 = 0.f;
#pragma unroll
            for (int p = 0; p < 4; ++p) {
                float4 c0 = *(const float4*)(cb + (size_t)j0 * DIM + p * 64 + d16 * 4);
                float4 c1 = *(const float4*)(cb + (size_t)j1 * DIM + p * 64 + d16 * 4);
                s0 = fmaf(xr[p].x, c0.x, s0); s0 = fmaf(xr[p].y, c0.y, s0);
                s0 = fmaf(xr[p].z, c0.z, s0); s0 = fmaf(xr[p].w, c0.w, s0);
                s1 = fmaf(xr[p].x, c1.x, s1); s1 = fmaf(xr[p].y, c1.y, s1);
                s1 = fmaf(xr[p].z, c1.z, s1); s1 = fmaf(xr[p].w, c1.w, s1);
            }
            // butterfly sum within each 16-lane code group
#pragma unroll
            for (int m = 1; m <= 8; m <<= 1) {
                s0 += __shfl_xor(s0, m, 64);
                s1 += __shfl_xor(s1, m, 64);
            }
            float d0 = cn[j0] - 2.0f * s0;
            float d1 = cn[j1] - 2.0f * s1;
            best = u64min(best, ((u64)sortable(d0) << 32) | (unsigned)j0);
            best = u64min(best, ((u64)sortable(d1) << 32) | (unsigned)j1);
        }
#pragma unroll
        for (int m = 1; m <= 32; m <<= 1) best = u64min(best, shfl64x(best, m));
        if (lane == 0) wbest[w] = best;
        __syncthreads();
        if (tid == 0) {
            u64 b = u64min(u64min(wbest[0], wbest[1]), u64min(wbest[2], wbest[3]));
            idx32[row] = (unsigned)(b & 0xffffffffu);
        }
        __syncthreads();   // xs/wbest reuse safety for next li
    }
}

// gather codebook rows, write quantized + tokens, per-block loss partial, histogram
__global__ void vq_gather(const float* __restrict__ inp, const float* __restrict__ cb,
                          const unsigned* __restrict__ idx32, float* __restrict__ out,
                          float* __restrict__ losspart, unsigned int* __restrict__ hist) {
    __shared__ float red[4];
    int w = threadIdx.x >> 6, lane = threadIdx.x & 63;
    int i = blockIdx.x * 4 + w;
    unsigned idx = idx32[i];
    float4 c = ((const float4*)(cb + (size_t)idx * DIM))[lane];
    float4 x = ((const float4*)(inp + (size_t)i * DIM))[lane];
    ((float4*)(out + OUT_Q))[(size_t)i * 64 + lane] = c;
    float dx = c.x - x.x, dy = c.y - x.y, dz = c.z - x.z, dw = c.w - x.w;
    float s = dx * dx + dy * dy + dz * dz + dw * dw;
#pragma unroll
    for (int m = 32; m; m >>= 1) s += __shfl_xor(s, m, 64);
    if (lane == 0) {
        out[OUT_T + i] = (float)idx;
        red[w] = s;
        atomicAdd(&hist[idx], 1u);
    }
    __syncthreads();
    if (threadIdx.x == 0)
        losspart[blockIdx.x] = red[0] + red[1] + red[2] + red[3];
}

__global__ void vq_finalize(const unsigned int* __restrict__ hist,
                            const float* __restrict__ losspart, float* __restrict__ out) {
    __shared__ float redp[256], redl[256];
    int tid = threadIdx.x;
    float sp = 0.f, sl = 0.f;
    for (int k = tid; k < K_CODES; k += 256) {
        float p = (float)hist[k] * (1.0f / (float)N_ROWS);
        sp += p * logf(p + 1e-10f);
        sl += losspart[k];
    }
    redp[tid] = sp; redl[tid] = sl;
    __syncthreads();
    for (int st = 128; st; st >>= 1) {
        if (tid < st) { redp[tid] += redp[tid + st]; redl[tid] += redl[tid + st]; }
        __syncthreads();
    }
    if (tid == 0) {
        float perp = expf(-redp[0]);
        float e = redl[0] / 8388608.0f;      // mean((q - x)^2)
        out[OUT_S + 0] = 1.25f * e;          // vq_loss
        out[OUT_S + 1] = 0.25f * e;          // commitment_loss
        out[OUT_S + 2] = e;                  // codebook_loss
        out[OUT_S + 3] = perp;               // perplexity
    }
}

extern "C" void kernel_launch(void* const* d_in, const int* in_sizes, int n_in,
                              void* d_out, int out_size, void* d_ws, size_t ws_size,
                              hipStream_t stream) {
    const float* inp = (const float*)d_in[0];
    const float* cb = (const float*)d_in[1];
    float* out = (float*)d_out;
    char* ws = (char*)d_ws;
    u16* A = (u16*)(ws + A_OFF);
    u16* B = (u16*)(ws + B_OFF);
    float* cn = (float*)(ws + CN_OFF);
    u64x2* part = (u64x2*)(ws + PART_OFF);
    unsigned* idx32 = (unsigned*)(ws + IDX_OFF);
    unsigned int* hist = (unsigned int*)(ws + HIST_OFF);
    int* cnt = (int*)(ws + CNT_OFF);
    int* flaglist = (int*)(ws + FLAG_OFF);
    float* losspart = (float*)(ws + LOSS_OFF);

    hipMemsetAsync(hist, 0, K_CODES * 4 + 16, stream);   // hist + cnt

    prep<<<5120, 256, 0, stream>>>(inp, cb, A, B, cn);
    vq_pass1<<<dim3(N_ROWS / BM, JSPLIT), 256, 0, stream>>>(A, B, cn, part);
    vq_merge<<<N_ROWS / 256, 256, 0, stream>>>(part, idx32, flaglist, cnt);
    vq_recompute<<<1024, 256, 0, stream>>>(inp, cb, cn, flaglist, cnt, idx32);
    vq_gather<<<N_ROWS / 4, 256, 0, stream>>>(inp, cb, idx32, out, losspart, hist);
    vq_finalize<<<1, 256, 0, stream>>>(hist, losspart, out);
}

// Round 5
// 733.306 us; speedup vs baseline: 4.1902x; 2.0767x over previous
//
#include <hip/hip_runtime.h>
#include <stdint.h>

typedef unsigned short u16;
typedef unsigned long long u64;

#define N_ROWS 32768
#define DIM 256
#define K_CODES 8192
#define TAU 0.3f

// workspace offsets (bytes)
#define A_OFF     0ull            // 32768*256*2 = 16777216
#define B_OFF     16777216ull     // 8192*256*2  = 4194304
#define CN_OFF    20971520ull     // 8192*4
#define PART1_OFF 21004288ull     // 32768*4*8 = 1048576
#define PART2_OFF 22052864ull     // 32768*4*4 = 524288
#define IDX_OFF   22577152ull     // 32768*4
#define HIST_OFF  22708224ull     // 8192*4
#define CNT_OFF   22740992ull     // 16 (memset together with hist)
#define FLAG_OFF  22741008ull     // 32768*4
#define LOSS_OFF  22872080ull     // 8192*4

// output offsets (float elements)
#define OUT_Q 0
#define OUT_T 8388608
#define OUT_S 8421376

#define BM 128
#define BN 128
#define BK 64
#define JSPLIT 4

// packed sentinel: dist=+inf, idx=0xffffffff (any real (dist,idx) sorts below it)
#define PACK_INF ((((u64)0xFF800000u) << 32) | 0xFFFFFFFFull)

typedef _Float16 half8 __attribute__((ext_vector_type(8)));
typedef float floatx4 __attribute__((ext_vector_type(4)));

__device__ __forceinline__ void gload_lds16(const void* g, void* l) {
    __builtin_amdgcn_global_load_lds(
        (const __attribute__((address_space(1))) void*)g,
        (__attribute__((address_space(3))) void*)l,
        16, 0, 0);
}

__device__ __forceinline__ unsigned sortable(float v) {
    unsigned u = __float_as_uint(v);
    return (u & 0x80000000u) ? ~u : (u | 0x80000000u);
}
__device__ __forceinline__ float unsortable(unsigned u) {
    return (u & 0x80000000u) ? __uint_as_float(u & 0x7fffffffu) : __uint_as_float(~u);
}
__device__ __forceinline__ u64 shfl64x(u64 v, int m) {
    return ((u64)(unsigned)__shfl_xor((int)(v >> 32), m, 64) << 32) |
           (unsigned)__shfl_xor((int)(v & 0xffffffffu), m, 64);
}
__device__ __forceinline__ u64 u64min(u64 a, u64 b) { return a < b ? a : b; }
__device__ __forceinline__ u64 u64max(u64 a, u64 b) { return a > b ? a : b; }

// fp32 -> f16 (hi) cast for inputs and codebook; fused ||c||^2.
__global__ void prep(const float* __restrict__ inp, const float* __restrict__ cb,
                     u16* __restrict__ A, u16* __restrict__ B, float* __restrict__ cn) {
    int g = blockIdx.x * 256 + threadIdx.x;       // 40960 rows * 32 threads
    int row = g >> 5;
    int kc = (g & 31) << 3;
    bool isA = row < N_ROWS;
    const float* src = isA ? inp + (size_t)row * DIM + kc
                           : cb + (size_t)(row - N_ROWS) * DIM + kc;
    u16* dst = isA ? A + (size_t)row * DIM + kc
                   : B + (size_t)(row - N_ROWS) * DIM + kc;
    float4 x0 = *(const float4*)(src);
    float4 x1 = *(const float4*)(src + 4);
    float xs[8] = {x0.x, x0.y, x0.z, x0.w, x1.x, x1.y, x1.z, x1.w};
    half8 hv;
    float s = 0.f;
#pragma unroll
    for (int i = 0; i < 8; ++i) {
        hv[i] = (_Float16)xs[i];
        s = fmaf(xs[i], xs[i], s);
    }
    *(half8*)(dst) = hv;
    if (!isA) {
#pragma unroll
        for (int m = 1; m <= 16; m <<= 1) s += __shfl_xor(s, m, 64);
        if ((g & 31) == 0) cn[row - N_ROWS] = s;
    }
}

// pass 1: hi*hi K=256 f16 MFMA GEMM + per-row top-1(packed)+second-best-dist(f32).
// launch_bounds(256,2): unified VGPR/AGPR file -> 256 regs/thread total; the
// 64-AGPR acc + ~110 arch VGPRs (m1[16]=32, m2f[16]=16, frags=32) fit w/o spill.
__launch_bounds__(256, 2)
__global__ void vq_pass1(const u16* __restrict__ A, const u16* __restrict__ B,
                         const float* __restrict__ cn,
                         u64* __restrict__ part1, float* __restrict__ part2) {
    __shared__ __align__(16) _Float16 lsA[BM * BK];
    __shared__ __align__(16) _Float16 lsB[BN * BK];
    __shared__ u64 t1buf[BM];
    __shared__ float t2buf[BM];

    const int tid = threadIdx.x;
    const int lane = tid & 63;
    const int w = tid >> 6;
    const int wm = w >> 1, wn = w & 1;
    const int l15 = lane & 15;
    const int quad = lane >> 4;
    const int xm = l15 & 7;
    const int rowBase = blockIdx.x * BM;
    const int jBase = blockIdx.y * (K_CODES / JSPLIT);

    u64 m1[16];
    float m2f[16];
#pragma unroll
    for (int i = 0; i < 16; ++i) { m1[i] = PACK_INF; m2f[i] = __builtin_inff(); }

    const int str = tid >> 3;
    const int sk16 = tid & 7;

    for (int jc = 0; jc < (K_CODES / JSPLIT) / BN; ++jc) {
        const int colBase = jBase + jc * BN;
        floatx4 acc[4][4];
#pragma unroll
        for (int mi = 0; mi < 4; ++mi)
#pragma unroll
            for (int ni = 0; ni < 4; ++ni)
                acc[mi][ni] = (floatx4){0.f, 0.f, 0.f, 0.f};

#pragma unroll 1
        for (int kk = 0; kk < DIM; kk += BK) {
#pragma unroll
            for (int it = 0; it < 4; ++it) {
                int r = it * 32 + str;
                int cdat = sk16 ^ (r & 7);           // XOR-swizzled source chunk
                int ch = it * 256 + tid;
                gload_lds16(A + (size_t)(rowBase + r) * DIM + kk + cdat * 8,
                            (char*)lsA + ch * 16);
                gload_lds16(B + (size_t)(colBase + r) * DIM + kk + cdat * 8,
                            (char*)lsB + ch * 16);
            }
            __syncthreads();
#pragma unroll
            for (int s = 0; s < 2; ++s) {
                const int koff = ((s * 4 + quad) ^ xm) * 8;
                half8 af[4], bf[4];
#pragma unroll
                for (int mi = 0; mi < 4; ++mi)
                    af[mi] = *(const half8*)(lsA + (wm * 64 + mi * 16 + l15) * BK + koff);
#pragma unroll
                for (int ni = 0; ni < 4; ++ni)
                    bf[ni] = *(const half8*)(lsB + (wn * 64 + ni * 16 + l15) * BK + koff);
#pragma unroll
                for (int mi = 0; mi < 4; ++mi)
#pragma unroll
                    for (int ni = 0; ni < 4; ++ni)
                        acc[mi][ni] = __builtin_amdgcn_mfma_f32_16x16x32_f16(
                            af[mi], bf[ni], acc[mi][ni], 0, 0, 0);
            }
            __syncthreads();
        }

        // top-2 insert (branchless); C/D layout col=lane&15, row=quad*4+reg
#pragma unroll
        for (int ni = 0; ni < 4; ++ni) {
            int j = colBase + wn * 64 + ni * 16 + l15;
            float cnj = cn[j];
#pragma unroll
            for (int mi = 0; mi < 4; ++mi) {
#pragma unroll
                for (int r = 0; r < 4; ++r) {
                    float val = cnj - 2.0f * acc[mi][ni][r];
                    u64 pk = ((u64)sortable(val) << 32) | (unsigned)j;
                    int tr = mi * 4 + r;
                    bool lt = pk < m1[tr];
                    float old1 = unsortable((unsigned)(m1[tr] >> 32));
                    m2f[tr] = lt ? old1 : fminf(m2f[tr], val);
                    m1[tr] = lt ? pk : m1[tr];
                }
            }
        }
    }

    // merge across the 16 lanes sharing each row
#pragma unroll
    for (int m = 1; m <= 8; m <<= 1)
#pragma unroll
        for (int tr = 0; tr < 16; ++tr) {
            u64 o1 = shfl64x(m1[tr], m);
            float o2 = __shfl_xor(m2f[tr], m, 64);
            u64 n1 = u64min(m1[tr], o1);
            float big = unsortable((unsigned)(u64max(m1[tr], o1) >> 32));
            m2f[tr] = fminf(big, fminf(m2f[tr], o2));
            m1[tr] = n1;
        }

    // merge the two column-half waves (wn=0 publishes, wn=1 merges & writes)
    if (wn == 0 && l15 == 0) {
#pragma unroll
        for (int tr = 0; tr < 16; ++tr) {
            int rl = wm * 64 + (tr >> 2) * 16 + quad * 4 + (tr & 3);
            t1buf[rl] = m1[tr]; t2buf[rl] = m2f[tr];
        }
    }
    __syncthreads();
    if (wn == 1 && l15 == 0) {
#pragma unroll
        for (int tr = 0; tr < 16; ++tr) {
            int rl = wm * 64 + (tr >> 2) * 16 + quad * 4 + (tr & 3);
            u64 o1 = t1buf[rl];
            float o2 = t2buf[rl];
            u64 n1 = u64min(m1[tr], o1);
            float big = unsortable((unsigned)(u64max(m1[tr], o1) >> 32));
            float n2 = fminf(big, fminf(m2f[tr], o2));
            size_t p = (size_t)(rowBase + rl) * JSPLIT + blockIdx.y;
            part1[p] = n1;
            part2[p] = n2;
        }
    }
}

// merge JSPLIT partial top-2s; emit idx + flag near-ties for exact recompute
__global__ void vq_merge(const u64* __restrict__ part1, const float* __restrict__ part2,
                         unsigned* __restrict__ idx32,
                         int* __restrict__ flaglist, int* __restrict__ cnt) {
    int row = blockIdx.x * 256 + threadIdx.x;
    u64 m1 = PACK_INF;
    float f2 = __builtin_inff();
#pragma unroll
    for (int y = 0; y < JSPLIT; ++y) {
        u64 p1 = part1[(size_t)row * JSPLIT + y];
        float p2 = part2[(size_t)row * JSPLIT + y];
        u64 n1 = u64min(m1, p1);
        float big = unsortable((unsigned)(u64max(m1, p1) >> 32));
        f2 = fminf(big, fminf(f2, p2));
        m1 = n1;
    }
    idx32[row] = (unsigned)(m1 & 0xffffffffu);
    float f1 = unsortable((unsigned)(m1 >> 32));
    if (f2 - f1 < TAU) {
        int p = atomicAdd(cnt, 1);
        flaglist[p] = row;
    }
}

// exact fp32 full-scan argmin for flagged rows.
// One BLOCK per row; 4 waves split the 8192 codes; lane = (c4, d16):
// 4 codes x 16 dim-lanes per load -> 256B-coalesced segments, 8 loads in flight.
__global__ void vq_recompute(const float* __restrict__ inp, const float* __restrict__ cb,
                             const float* __restrict__ cn, const int* __restrict__ flaglist,
                             const int* __restrict__ cnt, unsigned* __restrict__ idx32) {
    __shared__ float xs[DIM];
    __shared__ u64 wbest[4];
    const int tid = threadIdx.x;
    const int w = tid >> 6, lane = tid & 63;
    const int c4 = lane >> 4;      // code within group of 4
    const int d16 = lane & 15;     // dim-lane
    const int n = *cnt;
    for (int li = blockIdx.x; li < n; li += 1024) {
        int row = flaglist[li];
        if (tid < 64)
            ((float4*)xs)[tid] = ((const float4*)(inp + (size_t)row * DIM))[tid];
        __syncthreads();
        float4 xr[4];
#pragma unroll
        for (int p = 0; p < 4; ++p) xr[p] = *(const float4*)&xs[p * 64 + d16 * 4];

        u64 best = ~0ull;
        // wave w covers codes [w*2048, (w+1)*2048), 8 codes (2 groups) per iter
        for (int jb = w * 2048; jb < (w + 1) * 2048; jb += 8) {
            int j0 = jb + c4, j1 = jb + 4 + c4;
            float s0 = 0.f, s1 = 0.f;
#pragma unroll
            for (int p = 0; p < 4; ++p) {
                float4 c0 = *(const float4*)(cb + (size_t)j0 * DIM + p * 64 + d16 * 4);
                float4 c1 = *(const float4*)(cb + (size_t)j1 * DIM + p * 64 + d16 * 4);
                s0 = fmaf(xr[p].x, c0.x, s0); s0 = fmaf(xr[p].y, c0.y, s0);
                s0 = fmaf(xr[p].z, c0.z, s0); s0 = fmaf(xr[p].w, c0.w, s0);
                s1 = fmaf(xr[p].x, c1.x, s1); s1 = fmaf(xr[p].y, c1.y, s1);
                s1 = fmaf(xr[p].z, c1.z, s1); s1 = fmaf(xr[p].w, c1.w, s1);
            }
            // butterfly sum within each 16-lane code group
#pragma unroll
            for (int m = 1; m <= 8; m <<= 1) {
                s0 += __shfl_xor(s0, m, 64);
                s1 += __shfl_xor(s1, m, 64);
            }
            float d0 = cn[j0] - 2.0f * s0;
            float d1 = cn[j1] - 2.0f * s1;
            best = u64min(best, ((u64)sortable(d0) << 32) | (unsigned)j0);
            best = u64min(best, ((u64)sortable(d1) << 32) | (unsigned)j1);
        }
#pragma unroll
        for (int m = 1; m <= 32; m <<= 1) best = u64min(best, shfl64x(best, m));
        if (lane == 0) wbest[w] = best;
        __syncthreads();
        if (tid == 0) {
            u64 b = u64min(u64min(wbest[0], wbest[1]), u64min(wbest[2], wbest[3]));
            idx32[row] = (unsigned)(b & 0xffffffffu);
        }
        __syncthreads();   // xs/wbest reuse safety for next li
    }
}

// gather codebook rows, write quantized + tokens, per-block loss partial, histogram
__global__ void vq_gather(const float* __restrict__ inp, const float* __restrict__ cb,
                          const unsigned* __restrict__ idx32, float* __restrict__ out,
                          float* __restrict__ losspart, unsigned int* __restrict__ hist) {
    __shared__ float red[4];
    int w = threadIdx.x >> 6, lane = threadIdx.x & 63;
    int i = blockIdx.x * 4 + w;
    unsigned idx = idx32[i];
    float4 c = ((const float4*)(cb + (size_t)idx * DIM))[lane];
    float4 x = ((const float4*)(inp + (size_t)i * DIM))[lane];
    ((float4*)(out + OUT_Q))[(size_t)i * 64 + lane] = c;
    float dx = c.x - x.x, dy = c.y - x.y, dz = c.z - x.z, dw = c.w - x.w;
    float s = dx * dx + dy * dy + dz * dz + dw * dw;
#pragma unroll
    for (int m = 32; m; m >>= 1) s += __shfl_xor(s, m, 64);
    if (lane == 0) {
        out[OUT_T + i] = (float)idx;
        red[w] = s;
        atomicAdd(&hist[idx], 1u);
    }
    __syncthreads();
    if (threadIdx.x == 0)
        losspart[blockIdx.x] = red[0] + red[1] + red[2] + red[3];
}

__global__ void vq_finalize(const unsigned int* __restrict__ hist,
                            const float* __restrict__ losspart, float* __restrict__ out) {
    __shared__ float redp[256], redl[256];
    int tid = threadIdx.x;
    float sp = 0.f, sl = 0.f;
    for (int k = tid; k < K_CODES; k += 256) {
        float p = (float)hist[k] * (1.0f / (float)N_ROWS);
        sp += p * logf(p + 1e-10f);
        sl += losspart[k];
    }
    redp[tid] = sp; redl[tid] = sl;
    __syncthreads();
    for (int st = 128; st; st >>= 1) {
        if (tid < st) { redp[tid] += redp[tid + st]; redl[tid] += redl[tid + st]; }
        __syncthreads();
    }
    if (tid == 0) {
        float perp = expf(-redp[0]);
        float e = redl[0] / 8388608.0f;      // mean((q - x)^2)
        out[OUT_S + 0] = 1.25f * e;          // vq_loss
        out[OUT_S + 1] = 0.25f * e;          // commitment_loss
        out[OUT_S + 2] = e;                  // codebook_loss
        out[OUT_S + 3] = perp;               // perplexity
    }
}

extern "C" void kernel_launch(void* const* d_in, const int* in_sizes, int n_in,
                              void* d_out, int out_size, void* d_ws, size_t ws_size,
                              hipStream_t stream) {
    const float* inp = (const float*)d_in[0];
    const float* cb = (const float*)d_in[1];
    float* out = (float*)d_out;
    char* ws = (char*)d_ws;
    u16* A = (u16*)(ws + A_OFF);
    u16* B = (u16*)(ws + B_OFF);
    float* cn = (float*)(ws + CN_OFF);
    u64* part1 = (u64*)(ws + PART1_OFF);
    float* part2 = (float*)(ws + PART2_OFF);
    unsigned* idx32 = (unsigned*)(ws + IDX_OFF);
    unsigned int* hist = (unsigned int*)(ws + HIST_OFF);
    int* cnt = (int*)(ws + CNT_OFF);
    int* flaglist = (int*)(ws + FLAG_OFF);
    float* losspart = (float*)(ws + LOSS_OFF);

    hipMemsetAsync(hist, 0, K_CODES * 4 + 16, stream);   // hist + cnt

    prep<<<5120, 256, 0, stream>>>(inp, cb, A, B, cn);
    vq_pass1<<<dim3(N_ROWS / BM, JSPLIT), 256, 0, stream>>>(A, B, cn, part1, part2);
    vq_merge<<<N_ROWS / 256, 256, 0, stream>>>(part1, part2, idx32, flaglist, cnt);
    vq_recompute<<<1024, 256, 0, stream>>>(inp, cb, cn, flaglist, cnt, idx32);
    vq_gather<<<N_ROWS / 4, 256, 0, stream>>>(inp, cb, idx32, out, losspart, hist);
    vq_finalize<<<1, 256, 0, stream>>>(hist, losspart, out);
}

// Round 6
// 588.578 us; speedup vs baseline: 5.2206x; 1.2459x over previous
//
#include <hip/hip_runtime.h>
#include <stdint.h>

typedef unsigned short u16;
typedef unsigned long long u64;

#define N_ROWS 32768
#define DIM 256
#define K_CODES 8192
#define TAU 0.3f

// workspace offsets (bytes)
#define A_OFF     0ull            // 32768*256*2 = 16777216
#define B_OFF     16777216ull     // 8192*256*2  = 4194304
#define CN_OFF    20971520ull     // 8192*4
#define PART1_OFF 21004288ull     // 32768*4*8 = 1048576
#define PART2_OFF 22052864ull     // 32768*4*4 = 524288
#define IDX_OFF   22577152ull     // 32768*4
#define HIST_OFF  22708224ull     // 8192*4
#define CNT_OFF   22740992ull     // 16 (memset together with hist)
#define FLAG_OFF  22741008ull     // 32768*4
#define LOSS_OFF  22872080ull     // 8192*4
#define CBT_OFF   23068672ull     // 256*8192*4 = 8388608 (codebook transposed)

// output offsets (float elements)
#define OUT_Q 0
#define OUT_T 8388608
#define OUT_S 8421376

#define BM 128
#define BN 128
#define BK 64
#define JSPLIT 4

// packed sentinel: dist=+inf, idx=0xffffffff (any real (dist,idx) sorts below it)
#define PACK_INF ((((u64)0xFF800000u) << 32) | 0xFFFFFFFFull)

typedef _Float16 half8 __attribute__((ext_vector_type(8)));
typedef float floatx4 __attribute__((ext_vector_type(4)));

__device__ __forceinline__ void gload_lds16(const void* g, void* l) {
    __builtin_amdgcn_global_load_lds(
        (const __attribute__((address_space(1))) void*)g,
        (__attribute__((address_space(3))) void*)l,
        16, 0, 0);
}

__device__ __forceinline__ unsigned sortable(float v) {
    unsigned u = __float_as_uint(v);
    return (u & 0x80000000u) ? ~u : (u | 0x80000000u);
}
__device__ __forceinline__ float unsortable(unsigned u) {
    return (u & 0x80000000u) ? __uint_as_float(u & 0x7fffffffu) : __uint_as_float(~u);
}
__device__ __forceinline__ u64 shfl64x(u64 v, int m) {
    return ((u64)(unsigned)__shfl_xor((int)(v >> 32), m, 64) << 32) |
           (unsigned)__shfl_xor((int)(v & 0xffffffffu), m, 64);
}
__device__ __forceinline__ u64 u64min(u64 a, u64 b) { return a < b ? a : b; }
__device__ __forceinline__ u64 u64max(u64 a, u64 b) { return a > b ? a : b; }

// fp32 -> f16 (hi) cast for inputs and codebook; fused ||c||^2.
__global__ void prep(const float* __restrict__ inp, const float* __restrict__ cb,
                     u16* __restrict__ A, u16* __restrict__ B, float* __restrict__ cn) {
    int g = blockIdx.x * 256 + threadIdx.x;       // 40960 rows * 32 threads
    int row = g >> 5;
    int kc = (g & 31) << 3;
    bool isA = row < N_ROWS;
    const float* src = isA ? inp + (size_t)row * DIM + kc
                           : cb + (size_t)(row - N_ROWS) * DIM + kc;
    u16* dst = isA ? A + (size_t)row * DIM + kc
                   : B + (size_t)(row - N_ROWS) * DIM + kc;
    float4 x0 = *(const float4*)(src);
    float4 x1 = *(const float4*)(src + 4);
    float xs[8] = {x0.x, x0.y, x0.z, x0.w, x1.x, x1.y, x1.z, x1.w};
    half8 hv;
    float s = 0.f;
#pragma unroll
    for (int i = 0; i < 8; ++i) {
        hv[i] = (_Float16)xs[i];
        s = fmaf(xs[i], xs[i], s);
    }
    *(half8*)(dst) = hv;
    if (!isA) {
#pragma unroll
        for (int m = 1; m <= 16; m <<= 1) s += __shfl_xor(s, m, 64);
        if ((g & 31) == 0) cn[row - N_ROWS] = s;
    }
}

// LDS-tiled transpose: cbT[d][j] = cb[j][d]. 64x64 tiles.
__global__ void transpose_cb(const float* __restrict__ cb, float* __restrict__ cbT) {
    __shared__ float tile[64][65];
    const int tid = threadIdx.x;
    const int tj = blockIdx.x * 64;     // code-tile base
    const int td = blockIdx.y * 64;     // dim-tile base
    const int c = (tid & 15) * 4;
    const int r0 = tid >> 4;
#pragma unroll
    for (int p = 0; p < 4; ++p) {
        int r = p * 16 + r0;
        float4 v = *(const float4*)(cb + (size_t)(tj + r) * DIM + td + c);
        tile[r][c] = v.x; tile[r][c + 1] = v.y; tile[r][c + 2] = v.z; tile[r][c + 3] = v.w;
    }
    __syncthreads();
#pragma unroll
    for (int p = 0; p < 4; ++p) {
        int rr = p * 16 + r0;
        float4 w = {tile[c][rr], tile[c + 1][rr], tile[c + 2][rr], tile[c + 3][rr]};
        *(float4*)(cbT + (size_t)(td + rr) * K_CODES + tj + c) = w;
    }
}

// pass 1: hi*hi K=256 f16 MFMA GEMM + per-row top-1(packed)+second-best-dist(f32).
// launch_bounds(256,2): unified VGPR/AGPR file -> 256 regs/thread total; the
// 64-AGPR acc + ~110 arch VGPRs fit w/o spill.
__launch_bounds__(256, 2)
__global__ void vq_pass1(const u16* __restrict__ A, const u16* __restrict__ B,
                         const float* __restrict__ cn,
                         u64* __restrict__ part1, float* __restrict__ part2) {
    __shared__ __align__(16) _Float16 lsA[BM * BK];
    __shared__ __align__(16) _Float16 lsB[BN * BK];
    __shared__ u64 t1buf[BM];
    __shared__ float t2buf[BM];

    const int tid = threadIdx.x;
    const int lane = tid & 63;
    const int w = tid >> 6;
    const int wm = w >> 1, wn = w & 1;
    const int l15 = lane & 15;
    const int quad = lane >> 4;
    const int xm = l15 & 7;
    const int rowBase = blockIdx.x * BM;
    const int jBase = blockIdx.y * (K_CODES / JSPLIT);

    u64 m1[16];
    float m2f[16];
#pragma unroll
    for (int i = 0; i < 16; ++i) { m1[i] = PACK_INF; m2f[i] = __builtin_inff(); }

    const int str = tid >> 3;
    const int sk16 = tid & 7;

    for (int jc = 0; jc < (K_CODES / JSPLIT) / BN; ++jc) {
        const int colBase = jBase + jc * BN;
        floatx4 acc[4][4];
#pragma unroll
        for (int mi = 0; mi < 4; ++mi)
#pragma unroll
            for (int ni = 0; ni < 4; ++ni)
                acc[mi][ni] = (floatx4){0.f, 0.f, 0.f, 0.f};

#pragma unroll 1
        for (int kk = 0; kk < DIM; kk += BK) {
#pragma unroll
            for (int it = 0; it < 4; ++it) {
                int r = it * 32 + str;
                int cdat = sk16 ^ (r & 7);           // XOR-swizzled source chunk
                int ch = it * 256 + tid;
                gload_lds16(A + (size_t)(rowBase + r) * DIM + kk + cdat * 8,
                            (char*)lsA + ch * 16);
                gload_lds16(B + (size_t)(colBase + r) * DIM + kk + cdat * 8,
                            (char*)lsB + ch * 16);
            }
            __syncthreads();
#pragma unroll
            for (int s = 0; s < 2; ++s) {
                const int koff = ((s * 4 + quad) ^ xm) * 8;
                half8 af[4], bf[4];
#pragma unroll
                for (int mi = 0; mi < 4; ++mi)
                    af[mi] = *(const half8*)(lsA + (wm * 64 + mi * 16 + l15) * BK + koff);
#pragma unroll
                for (int ni = 0; ni < 4; ++ni)
                    bf[ni] = *(const half8*)(lsB + (wn * 64 + ni * 16 + l15) * BK + koff);
#pragma unroll
                for (int mi = 0; mi < 4; ++mi)
#pragma unroll
                    for (int ni = 0; ni < 4; ++ni)
                        acc[mi][ni] = __builtin_amdgcn_mfma_f32_16x16x32_f16(
                            af[mi], bf[ni], acc[mi][ni], 0, 0, 0);
            }
            __syncthreads();
        }

        // top-2 insert (branchless); C/D layout col=lane&15, row=quad*4+reg
#pragma unroll
        for (int ni = 0; ni < 4; ++ni) {
            int j = colBase + wn * 64 + ni * 16 + l15;
            float cnj = cn[j];
#pragma unroll
            for (int mi = 0; mi < 4; ++mi) {
#pragma unroll
                for (int r = 0; r < 4; ++r) {
                    float val = cnj - 2.0f * acc[mi][ni][r];
                    u64 pk = ((u64)sortable(val) << 32) | (unsigned)j;
                    int tr = mi * 4 + r;
                    bool lt = pk < m1[tr];
                    float old1 = unsortable((unsigned)(m1[tr] >> 32));
                    m2f[tr] = lt ? old1 : fminf(m2f[tr], val);
                    m1[tr] = lt ? pk : m1[tr];
                }
            }
        }
    }

    // merge across the 16 lanes sharing each row
#pragma unroll
    for (int m = 1; m <= 8; m <<= 1)
#pragma unroll
        for (int tr = 0; tr < 16; ++tr) {
            u64 o1 = shfl64x(m1[tr], m);
            float o2 = __shfl_xor(m2f[tr], m, 64);
            u64 n1 = u64min(m1[tr], o1);
            float big = unsortable((unsigned)(u64max(m1[tr], o1) >> 32));
            m2f[tr] = fminf(big, fminf(m2f[tr], o2));
            m1[tr] = n1;
        }

    // merge the two column-half waves (wn=0 publishes, wn=1 merges & writes)
    if (wn == 0 && l15 == 0) {
#pragma unroll
        for (int tr = 0; tr < 16; ++tr) {
            int rl = wm * 64 + (tr >> 2) * 16 + quad * 4 + (tr & 3);
            t1buf[rl] = m1[tr]; t2buf[rl] = m2f[tr];
        }
    }
    __syncthreads();
    if (wn == 1 && l15 == 0) {
#pragma unroll
        for (int tr = 0; tr < 16; ++tr) {
            int rl = wm * 64 + (tr >> 2) * 16 + quad * 4 + (tr & 3);
            u64 o1 = t1buf[rl];
            float o2 = t2buf[rl];
            u64 n1 = u64min(m1[tr], o1);
            float big = unsortable((unsigned)(u64max(m1[tr], o1) >> 32));
            float n2 = fminf(big, fminf(m2f[tr], o2));
            size_t p = (size_t)(rowBase + rl) * JSPLIT + blockIdx.y;
            part1[p] = n1;
            part2[p] = n2;
        }
    }
}

// merge JSPLIT partial top-2s; emit idx + flag near-ties for exact recompute
__global__ void vq_merge(const u64* __restrict__ part1, const float* __restrict__ part2,
                         unsigned* __restrict__ idx32,
                         int* __restrict__ flaglist, int* __restrict__ cnt) {
    int row = blockIdx.x * 256 + threadIdx.x;
    u64 m1 = PACK_INF;
    float f2 = __builtin_inff();
#pragma unroll
    for (int y = 0; y < JSPLIT; ++y) {
        u64 p1 = part1[(size_t)row * JSPLIT + y];
        float p2 = part2[(size_t)row * JSPLIT + y];
        u64 n1 = u64min(m1, p1);
        float big = unsortable((unsigned)(u64max(m1, p1) >> 32));
        f2 = fminf(big, fminf(f2, p2));
        m1 = n1;
    }
    idx32[row] = (unsigned)(m1 & 0xffffffffu);
    float f1 = unsortable((unsigned)(m1 >> 32));
    if (f2 - f1 < TAU) {
        int p = atomicAdd(cnt, 1);
        flaglist[p] = row;
    }
}

// exact fp32 full-scan argmin for flagged rows, v3:
// one block = 8 flagged rows; cbT[d][j] streamed ONCE per block (coalesced
// float4 per thread = 4 codes); x rows transposed in LDS (broadcast b128
// reads); 32 fma per dim per thread; no cross-lane ops in the hot loop.
__global__ void vq_recompute(const float* __restrict__ inp, const float* __restrict__ cbT,
                             const float* __restrict__ cn, const int* __restrict__ flaglist,
                             const int* __restrict__ cnt, unsigned* __restrict__ idx32) {
    __shared__ float xsT[DIM][8];
    __shared__ u64 wred[4][8];
    const int tid = threadIdx.x;
    const int w = tid >> 6, lane = tid & 63;
    const int n = *cnt;
    const int base = blockIdx.x * 8;
    if (base >= n) return;

    // stage 8 rows transposed: thread group (tid>>5)=r loads dims (tid&31)*8..+7
    {
        int r = tid >> 5;
        int d0 = (tid & 31) * 8;
        int li = base + r;
        int row = flaglist[li < n ? li : (n - 1)];
        float4 a = *(const float4*)(inp + (size_t)row * DIM + d0);
        float4 b = *(const float4*)(inp + (size_t)row * DIM + d0 + 4);
        xsT[d0 + 0][r] = a.x; xsT[d0 + 1][r] = a.y; xsT[d0 + 2][r] = a.z; xsT[d0 + 3][r] = a.w;
        xsT[d0 + 4][r] = b.x; xsT[d0 + 5][r] = b.y; xsT[d0 + 6][r] = b.z; xsT[d0 + 7][r] = b.w;
    }
    __syncthreads();

    u64 best[8];
#pragma unroll
    for (int r = 0; r < 8; ++r) best[r] = PACK_INF;

    for (int chunk = 0; chunk < 8; ++chunk) {
        const int cbase = chunk * 1024 + tid * 4;   // this thread's 4 codes
        float4 acc[8];
#pragma unroll
        for (int r = 0; r < 8; ++r) acc[r] = (float4){0.f, 0.f, 0.f, 0.f};

#pragma unroll 4
        for (int d = 0; d < DIM; ++d) {
            float4 cv = *(const float4*)(cbT + (size_t)d * K_CODES + cbase);
            float4 xa = *(const float4*)&xsT[d][0];
            float4 xb = *(const float4*)&xsT[d][4];
            float xv[8] = {xa.x, xa.y, xa.z, xa.w, xb.x, xb.y, xb.z, xb.w};
#pragma unroll
            for (int r = 0; r < 8; ++r) {
                acc[r].x = fmaf(xv[r], cv.x, acc[r].x);
                acc[r].y = fmaf(xv[r], cv.y, acc[r].y);
                acc[r].z = fmaf(xv[r], cv.z, acc[r].z);
                acc[r].w = fmaf(xv[r], cv.w, acc[r].w);
            }
        }
        float4 cn4 = *(const float4*)(cn + cbase);
#pragma unroll
        for (int r = 0; r < 8; ++r) {
            float d0 = cn4.x - 2.0f * acc[r].x;
            float d1 = cn4.y - 2.0f * acc[r].y;
            float d2 = cn4.z - 2.0f * acc[r].z;
            float d3 = cn4.w - 2.0f * acc[r].w;
            best[r] = u64min(best[r], ((u64)sortable(d0) << 32) | (unsigned)(cbase + 0));
            best[r] = u64min(best[r], ((u64)sortable(d1) << 32) | (unsigned)(cbase + 1));
            best[r] = u64min(best[r], ((u64)sortable(d2) << 32) | (unsigned)(cbase + 2));
            best[r] = u64min(best[r], ((u64)sortable(d3) << 32) | (unsigned)(cbase + 3));
        }
    }

    // reduce across 64 lanes, then across 4 waves
#pragma unroll
    for (int m = 1; m <= 32; m <<= 1)
#pragma unroll
        for (int r = 0; r < 8; ++r) best[r] = u64min(best[r], shfl64x(best[r], m));
    if (lane < 8) wred[w][lane] = best[lane];
    __syncthreads();
    if (tid < 8) {
        u64 b = u64min(u64min(wred[0][tid], wred[1][tid]),
                       u64min(wred[2][tid], wred[3][tid]));
        if (base + tid < n)
            idx32[flaglist[base + tid]] = (unsigned)(b & 0xffffffffu);
    }
}

// gather codebook rows, write quantized + tokens, per-block loss partial, histogram
__global__ void vq_gather(const float* __restrict__ inp, const float* __restrict__ cb,
                          const unsigned* __restrict__ idx32, float* __restrict__ out,
                          float* __restrict__ losspart, unsigned int* __restrict__ hist) {
    __shared__ float red[4];
    int w = threadIdx.x >> 6, lane = threadIdx.x & 63;
    int i = blockIdx.x * 4 + w;
    unsigned idx = idx32[i];
    float4 c = ((const float4*)(cb + (size_t)idx * DIM))[lane];
    float4 x = ((const float4*)(inp + (size_t)i * DIM))[lane];
    ((float4*)(out + OUT_Q))[(size_t)i * 64 + lane] = c;
    float dx = c.x - x.x, dy = c.y - x.y, dz = c.z - x.z, dw = c.w - x.w;
    float s = dx * dx + dy * dy + dz * dz + dw * dw;
#pragma unroll
    for (int m = 32; m; m >>= 1) s += __shfl_xor(s, m, 64);
    if (lane == 0) {
        out[OUT_T + i] = (float)idx;
        red[w] = s;
        atomicAdd(&hist[idx], 1u);
    }
    __syncthreads();
    if (threadIdx.x == 0)
        losspart[blockIdx.x] = red[0] + red[1] + red[2] + red[3];
}

__global__ void vq_finalize(const unsigned int* __restrict__ hist,
                            const float* __restrict__ losspart, float* __restrict__ out) {
    __shared__ float redp[256], redl[256];
    int tid = threadIdx.x;
    float sp = 0.f, sl = 0.f;
    for (int k = tid; k < K_CODES; k += 256) {
        float p = (float)hist[k] * (1.0f / (float)N_ROWS);
        sp += p * logf(p + 1e-10f);
        sl += losspart[k];
    }
    redp[tid] = sp; redl[tid] = sl;
    __syncthreads();
    for (int st = 128; st; st >>= 1) {
        if (tid < st) { redp[tid] += redp[tid + st]; redl[tid] += redl[tid + st]; }
        __syncthreads();
    }
    if (tid == 0) {
        float perp = expf(-redp[0]);
        float e = redl[0] / 8388608.0f;      // mean((q - x)^2)
        out[OUT_S + 0] = 1.25f * e;          // vq_loss
        out[OUT_S + 1] = 0.25f * e;          // commitment_loss
        out[OUT_S + 2] = e;                  // codebook_loss
        out[OUT_S + 3] = perp;               // perplexity
    }
}

extern "C" void kernel_launch(void* const* d_in, const int* in_sizes, int n_in,
                              void* d_out, int out_size, void* d_ws, size_t ws_size,
                              hipStream_t stream) {
    const float* inp = (const float*)d_in[0];
    const float* cb = (const float*)d_in[1];
    float* out = (float*)d_out;
    char* ws = (char*)d_ws;
    u16* A = (u16*)(ws + A_OFF);
    u16* B = (u16*)(ws + B_OFF);
    float* cn = (float*)(ws + CN_OFF);
    u64* part1 = (u64*)(ws + PART1_OFF);
    float* part2 = (float*)(ws + PART2_OFF);
    unsigned* idx32 = (unsigned*)(ws + IDX_OFF);
    unsigned int* hist = (unsigned int*)(ws + HIST_OFF);
    int* cnt = (int*)(ws + CNT_OFF);
    int* flaglist = (int*)(ws + FLAG_OFF);
    float* losspart = (float*)(ws + LOSS_OFF);
    float* cbT = (float*)(ws + CBT_OFF);

    hipMemsetAsync(hist, 0, K_CODES * 4 + 16, stream);   // hist + cnt

    prep<<<5120, 256, 0, stream>>>(inp, cb, A, B, cn);
    transpose_cb<<<dim3(K_CODES / 64, DIM / 64), 256, 0, stream>>>(cb, cbT);
    vq_pass1<<<dim3(N_ROWS / BM, JSPLIT), 256, 0, stream>>>(A, B, cn, part1, part2);
    vq_merge<<<N_ROWS / 256, 256, 0, stream>>>(part1, part2, idx32, flaglist, cnt);
    vq_recompute<<<N_ROWS / 8, 256, 0, stream>>>(inp, cbT, cn, flaglist, cnt, idx32);
    vq_gather<<<N_ROWS / 4, 256, 0, stream>>>(inp, cb, idx32, out, losspart, hist);
    vq_finalize<<<1, 256, 0, stream>>>(hist, losspart, out);
}

// Round 7
// 577.691 us; speedup vs baseline: 5.3189x; 1.0188x over previous
//
#include <hip/hip_runtime.h>
#include <stdint.h>

typedef unsigned short u16;
typedef unsigned long long u64;

#define N_ROWS 32768
#define DIM 256
#define K_CODES 8192
#define TAU 0.3f

// workspace offsets (bytes)
#define A_OFF     0ull            // 32768*256*2 = 16777216
#define B_OFF     16777216ull     // 8192*256*2  = 4194304
#define CN_OFF    20971520ull     // 8192*4
#define PART1_OFF 21004288ull     // 32768*4*8 = 1048576
#define PART2_OFF 22052864ull     // 32768*4*4 = 524288
#define IDX_OFF   22577152ull     // 32768*4
#define HIST_OFF  22708224ull     // 8192*4
#define CNT_OFF   22740992ull     // 16 (memset together with hist)
#define FLAG_OFF  22741008ull     // 32768*4
#define LOSS_OFF  22872080ull     // 8192*4
#define CBT_OFF   23068672ull     // 256*8192*4 = 8388608 (codebook transposed)

// output offsets (float elements)
#define OUT_Q 0
#define OUT_T 8388608
#define OUT_S 8421376

#define BM 128
#define BN 128
#define BK 64
#define JSPLIT 4

// packed sentinel: dist=+inf, idx=0xffffffff (any real (dist,idx) sorts below it)
#define PACK_INF ((((u64)0xFF800000u) << 32) | 0xFFFFFFFFull)

typedef _Float16 half8 __attribute__((ext_vector_type(8)));
typedef float floatx4 __attribute__((ext_vector_type(4)));

__device__ __forceinline__ void gload_lds16(const void* g, void* l) {
    __builtin_amdgcn_global_load_lds(
        (const __attribute__((address_space(1))) void*)g,
        (__attribute__((address_space(3))) void*)l,
        16, 0, 0);
}

__device__ __forceinline__ unsigned sortable(float v) {
    unsigned u = __float_as_uint(v);
    return (u & 0x80000000u) ? ~u : (u | 0x80000000u);
}
__device__ __forceinline__ float unsortable(unsigned u) {
    return (u & 0x80000000u) ? __uint_as_float(u & 0x7fffffffu) : __uint_as_float(~u);
}
__device__ __forceinline__ u64 shfl64x(u64 v, int m) {
    return ((u64)(unsigned)__shfl_xor((int)(v >> 32), m, 64) << 32) |
           (unsigned)__shfl_xor((int)(v & 0xffffffffu), m, 64);
}
__device__ __forceinline__ u64 u64min(u64 a, u64 b) { return a < b ? a : b; }
__device__ __forceinline__ u64 u64max(u64 a, u64 b) { return a > b ? a : b; }

// fp32 -> f16 (hi) cast for inputs and codebook; fused ||c||^2.
__global__ void prep(const float* __restrict__ inp, const float* __restrict__ cb,
                     u16* __restrict__ A, u16* __restrict__ B, float* __restrict__ cn) {
    int g = blockIdx.x * 256 + threadIdx.x;       // 40960 rows * 32 threads
    int row = g >> 5;
    int kc = (g & 31) << 3;
    bool isA = row < N_ROWS;
    const float* src = isA ? inp + (size_t)row * DIM + kc
                           : cb + (size_t)(row - N_ROWS) * DIM + kc;
    u16* dst = isA ? A + (size_t)row * DIM + kc
                   : B + (size_t)(row - N_ROWS) * DIM + kc;
    float4 x0 = *(const float4*)(src);
    float4 x1 = *(const float4*)(src + 4);
    float xs[8] = {x0.x, x0.y, x0.z, x0.w, x1.x, x1.y, x1.z, x1.w};
    half8 hv;
    float s = 0.f;
#pragma unroll
    for (int i = 0; i < 8; ++i) {
        hv[i] = (_Float16)xs[i];
        s = fmaf(xs[i], xs[i], s);
    }
    *(half8*)(dst) = hv;
    if (!isA) {
#pragma unroll
        for (int m = 1; m <= 16; m <<= 1) s += __shfl_xor(s, m, 64);
        if ((g & 31) == 0) cn[row - N_ROWS] = s;
    }
}

// LDS-tiled transpose: cbT[d][j] = cb[j][d]. 64x64 tiles.
__global__ void transpose_cb(const float* __restrict__ cb, float* __restrict__ cbT) {
    __shared__ float tile[64][65];
    const int tid = threadIdx.x;
    const int tj = blockIdx.x * 64;     // code-tile base
    const int td = blockIdx.y * 64;     // dim-tile base
    const int c = (tid & 15) * 4;
    const int r0 = tid >> 4;
#pragma unroll
    for (int p = 0; p < 4; ++p) {
        int r = p * 16 + r0;
        float4 v = *(const float4*)(cb + (size_t)(tj + r) * DIM + td + c);
        tile[r][c] = v.x; tile[r][c + 1] = v.y; tile[r][c + 2] = v.z; tile[r][c + 3] = v.w;
    }
    __syncthreads();
#pragma unroll
    for (int p = 0; p < 4; ++p) {
        int rr = p * 16 + r0;
        float4 w = {tile[c][rr], tile[c + 1][rr], tile[c + 2][rr], tile[c + 3][rr]};
        *(float4*)(cbT + (size_t)(td + rr) * K_CODES + tj + c) = w;
    }
}

// pass 1: hi*hi K=256 f16 MFMA GEMM + per-row top-2.
// Hot-path top-2 insert tracks (d1 f32, idx u32, d2 f32) separately — 6 VALU
// ops/element vs ~13 for packed-u64; strict < + increasing-j visit order
// preserves numpy first-occurrence tie-break. Pack to sortable u64 only at
// the cold final merge.
__launch_bounds__(256, 2)
__global__ void vq_pass1(const u16* __restrict__ A, const u16* __restrict__ B,
                         const float* __restrict__ cn,
                         u64* __restrict__ part1, float* __restrict__ part2) {
    __shared__ __align__(16) _Float16 lsA[BM * BK];
    __shared__ __align__(16) _Float16 lsB[BN * BK];
    __shared__ u64 t1buf[BM];
    __shared__ float t2buf[BM];

    const int tid = threadIdx.x;
    const int lane = tid & 63;
    const int w = tid >> 6;
    const int wm = w >> 1, wn = w & 1;
    const int l15 = lane & 15;
    const int quad = lane >> 4;
    const int xm = l15 & 7;
    const int rowBase = blockIdx.x * BM;
    const int jBase = blockIdx.y * (K_CODES / JSPLIT);

    float d1[16], d2[16];
    unsigned idxr[16];
#pragma unroll
    for (int i = 0; i < 16; ++i) {
        d1[i] = __builtin_inff(); d2[i] = __builtin_inff(); idxr[i] = 0xffffffffu;
    }

    const int str = tid >> 3;
    const int sk16 = tid & 7;

    for (int jc = 0; jc < (K_CODES / JSPLIT) / BN; ++jc) {
        const int colBase = jBase + jc * BN;
        floatx4 acc[4][4];
#pragma unroll
        for (int mi = 0; mi < 4; ++mi)
#pragma unroll
            for (int ni = 0; ni < 4; ++ni)
                acc[mi][ni] = (floatx4){0.f, 0.f, 0.f, 0.f};

#pragma unroll 1
        for (int kk = 0; kk < DIM; kk += BK) {
#pragma unroll
            for (int it = 0; it < 4; ++it) {
                int r = it * 32 + str;
                int cdat = sk16 ^ (r & 7);           // XOR-swizzled source chunk
                int ch = it * 256 + tid;
                gload_lds16(A + (size_t)(rowBase + r) * DIM + kk + cdat * 8,
                            (char*)lsA + ch * 16);
                gload_lds16(B + (size_t)(colBase + r) * DIM + kk + cdat * 8,
                            (char*)lsB + ch * 16);
            }
            __syncthreads();
#pragma unroll
            for (int s = 0; s < 2; ++s) {
                const int koff = ((s * 4 + quad) ^ xm) * 8;
                half8 af[4], bf[4];
#pragma unroll
                for (int mi = 0; mi < 4; ++mi)
                    af[mi] = *(const half8*)(lsA + (wm * 64 + mi * 16 + l15) * BK + koff);
#pragma unroll
                for (int ni = 0; ni < 4; ++ni)
                    bf[ni] = *(const half8*)(lsB + (wn * 64 + ni * 16 + l15) * BK + koff);
#pragma unroll
                for (int mi = 0; mi < 4; ++mi)
#pragma unroll
                    for (int ni = 0; ni < 4; ++ni)
                        acc[mi][ni] = __builtin_amdgcn_mfma_f32_16x16x32_f16(
                            af[mi], bf[ni], acc[mi][ni], 0, 0, 0);
            }
            __syncthreads();
        }

        // top-2 insert, 6 VALU/element; C/D layout col=lane&15, row=quad*4+reg
#pragma unroll
        for (int ni = 0; ni < 4; ++ni) {
            unsigned j = (unsigned)(colBase + wn * 64 + ni * 16 + l15);
            float cnj = cn[j];
#pragma unroll
            for (int mi = 0; mi < 4; ++mi) {
#pragma unroll
                for (int r = 0; r < 4; ++r) {
                    int tr = mi * 4 + r;
                    float val = fmaf(-2.0f, acc[mi][ni][r], cnj);
                    bool lt = val < d1[tr];
                    float sec = lt ? d1[tr] : val;
                    d2[tr] = fminf(d2[tr], sec);
                    d1[tr] = lt ? val : d1[tr];
                    idxr[tr] = lt ? j : idxr[tr];
                }
            }
        }
    }

    // pack (cold) and merge across the 16 lanes sharing each row
    u64 m1[16];
#pragma unroll
    for (int tr = 0; tr < 16; ++tr)
        m1[tr] = ((u64)sortable(d1[tr]) << 32) | idxr[tr];
#pragma unroll
    for (int m = 1; m <= 8; m <<= 1)
#pragma unroll
        for (int tr = 0; tr < 16; ++tr) {
            u64 o1 = shfl64x(m1[tr], m);
            float o2 = __shfl_xor(d2[tr], m, 64);
            u64 n1 = u64min(m1[tr], o1);
            float big = unsortable((unsigned)(u64max(m1[tr], o1) >> 32));
            d2[tr] = fminf(big, fminf(d2[tr], o2));
            m1[tr] = n1;
        }

    // merge the two column-half waves (wn=0 publishes, wn=1 merges & writes)
    if (wn == 0 && l15 == 0) {
#pragma unroll
        for (int tr = 0; tr < 16; ++tr) {
            int rl = wm * 64 + (tr >> 2) * 16 + quad * 4 + (tr & 3);
            t1buf[rl] = m1[tr]; t2buf[rl] = d2[tr];
        }
    }
    __syncthreads();
    if (wn == 1 && l15 == 0) {
#pragma unroll
        for (int tr = 0; tr < 16; ++tr) {
            int rl = wm * 64 + (tr >> 2) * 16 + quad * 4 + (tr & 3);
            u64 o1 = t1buf[rl];
            float o2 = t2buf[rl];
            u64 n1 = u64min(m1[tr], o1);
            float big = unsortable((unsigned)(u64max(m1[tr], o1) >> 32));
            float n2 = fminf(big, fminf(d2[tr], o2));
            size_t p = (size_t)(rowBase + rl) * JSPLIT + blockIdx.y;
            part1[p] = n1;
            part2[p] = n2;
        }
    }
}

// merge JSPLIT partial top-2s; emit idx + flag near-ties for exact recompute
__global__ void vq_merge(const u64* __restrict__ part1, const float* __restrict__ part2,
                         unsigned* __restrict__ idx32,
                         int* __restrict__ flaglist, int* __restrict__ cnt) {
    int row = blockIdx.x * 256 + threadIdx.x;
    u64 m1 = PACK_INF;
    float f2 = __builtin_inff();
#pragma unroll
    for (int y = 0; y < JSPLIT; ++y) {
        u64 p1 = part1[(size_t)row * JSPLIT + y];
        float p2 = part2[(size_t)row * JSPLIT + y];
        u64 n1 = u64min(m1, p1);
        float big = unsortable((unsigned)(u64max(m1, p1) >> 32));
        f2 = fminf(big, fminf(f2, p2));
        m1 = n1;
    }
    idx32[row] = (unsigned)(m1 & 0xffffffffu);
    float f1 = unsortable((unsigned)(m1 >> 32));
    if (f2 - f1 < TAU) {
        int p = atomicAdd(cnt, 1);
        flaglist[p] = row;
    }
}

// exact fp32 full-scan argmin for flagged rows, v4:
// one block = 8 flagged rows x 512 threads (8 waves share the codebook
// stream). cbT[d][j] read coalesced (thread owns 4 consecutive codes);
// x rows transposed in LDS (broadcast b128 reads); no cross-lane ops in
// the hot loop.
__global__ void vq_recompute(const float* __restrict__ inp, const float* __restrict__ cbT,
                             const float* __restrict__ cn, const int* __restrict__ flaglist,
                             const int* __restrict__ cnt, unsigned* __restrict__ idx32) {
    __shared__ float xsT[DIM][8];
    __shared__ u64 wred[8][8];
    const int tid = threadIdx.x;
    const int w = tid >> 6, lane = tid & 63;
    const int n = *cnt;
    const int base = blockIdx.x * 8;
    if (base >= n) return;

    // stage 8 rows transposed: wave w loads row (base+w), lane covers 4 dims
    {
        int li = base + w;
        int row = flaglist[li < n ? li : (n - 1)];
        float4 a = ((const float4*)(inp + (size_t)row * DIM))[lane];
        int d0 = lane * 4;
        xsT[d0 + 0][w] = a.x; xsT[d0 + 1][w] = a.y;
        xsT[d0 + 2][w] = a.z; xsT[d0 + 3][w] = a.w;
    }
    __syncthreads();

    u64 best[8];
#pragma unroll
    for (int r = 0; r < 8; ++r) best[r] = PACK_INF;

    for (int chunk = 0; chunk < 4; ++chunk) {
        const int cbase = chunk * 2048 + tid * 4;   // this thread's 4 codes
        float4 acc[8];
#pragma unroll
        for (int r = 0; r < 8; ++r) acc[r] = (float4){0.f, 0.f, 0.f, 0.f};

#pragma unroll 4
        for (int d = 0; d < DIM; ++d) {
            float4 cv = *(const float4*)(cbT + (size_t)d * K_CODES + cbase);
            float4 xa = *(const float4*)&xsT[d][0];
            float4 xb = *(const float4*)&xsT[d][4];
            float xv[8] = {xa.x, xa.y, xa.z, xa.w, xb.x, xb.y, xb.z, xb.w};
#pragma unroll
            for (int r = 0; r < 8; ++r) {
                acc[r].x = fmaf(xv[r], cv.x, acc[r].x);
                acc[r].y = fmaf(xv[r], cv.y, acc[r].y);
                acc[r].z = fmaf(xv[r], cv.z, acc[r].z);
                acc[r].w = fmaf(xv[r], cv.w, acc[r].w);
            }
        }
        float4 cn4 = *(const float4*)(cn + cbase);
#pragma unroll
        for (int r = 0; r < 8; ++r) {
            float d0 = cn4.x - 2.0f * acc[r].x;
            float d1 = cn4.y - 2.0f * acc[r].y;
            float d2 = cn4.z - 2.0f * acc[r].z;
            float d3 = cn4.w - 2.0f * acc[r].w;
            best[r] = u64min(best[r], ((u64)sortable(d0) << 32) | (unsigned)(cbase + 0));
            best[r] = u64min(best[r], ((u64)sortable(d1) << 32) | (unsigned)(cbase + 1));
            best[r] = u64min(best[r], ((u64)sortable(d2) << 32) | (unsigned)(cbase + 2));
            best[r] = u64min(best[r], ((u64)sortable(d3) << 32) | (unsigned)(cbase + 3));
        }
    }

    // reduce across 64 lanes, then across 8 waves
#pragma unroll
    for (int m = 1; m <= 32; m <<= 1)
#pragma unroll
        for (int r = 0; r < 8; ++r) best[r] = u64min(best[r], shfl64x(best[r], m));
    if (lane < 8) wred[w][lane] = best[lane];
    __syncthreads();
    if (tid < 8) {
        u64 b = wred[0][tid];
#pragma unroll
        for (int ww = 1; ww < 8; ++ww) b = u64min(b, wred[ww][tid]);
        if (base + tid < n)
            idx32[flaglist[base + tid]] = (unsigned)(b & 0xffffffffu);
    }
}

// gather codebook rows, write quantized + tokens, per-block loss partial, histogram
__global__ void vq_gather(const float* __restrict__ inp, const float* __restrict__ cb,
                          const unsigned* __restrict__ idx32, float* __restrict__ out,
                          float* __restrict__ losspart, unsigned int* __restrict__ hist) {
    __shared__ float red[4];
    int w = threadIdx.x >> 6, lane = threadIdx.x & 63;
    int i = blockIdx.x * 4 + w;
    unsigned idx = idx32[i];
    float4 c = ((const float4*)(cb + (size_t)idx * DIM))[lane];
    float4 x = ((const float4*)(inp + (size_t)i * DIM))[lane];
    ((float4*)(out + OUT_Q))[(size_t)i * 64 + lane] = c;
    float dx = c.x - x.x, dy = c.y - x.y, dz = c.z - x.z, dw = c.w - x.w;
    float s = dx * dx + dy * dy + dz * dz + dw * dw;
#pragma unroll
    for (int m = 32; m; m >>= 1) s += __shfl_xor(s, m, 64);
    if (lane == 0) {
        out[OUT_T + i] = (float)idx;
        red[w] = s;
        atomicAdd(&hist[idx], 1u);
    }
    __syncthreads();
    if (threadIdx.x == 0)
        losspart[blockIdx.x] = red[0] + red[1] + red[2] + red[3];
}

__global__ void vq_finalize(const unsigned int* __restrict__ hist,
                            const float* __restrict__ losspart, float* __restrict__ out) {
    __shared__ float redp[256], redl[256];
    int tid = threadIdx.x;
    float sp = 0.f, sl = 0.f;
    for (int k = tid; k < K_CODES; k += 256) {
        float p = (float)hist[k] * (1.0f / (float)N_ROWS);
        sp += p * logf(p + 1e-10f);
        sl += losspart[k];
    }
    redp[tid] = sp; redl[tid] = sl;
    __syncthreads();
    for (int st = 128; st; st >>= 1) {
        if (tid < st) { redp[tid] += redp[tid + st]; redl[tid] += redl[tid + st]; }
        __syncthreads();
    }
    if (tid == 0) {
        float perp = expf(-redp[0]);
        float e = redl[0] / 8388608.0f;      // mean((q - x)^2)
        out[OUT_S + 0] = 1.25f * e;          // vq_loss
        out[OUT_S + 1] = 0.25f * e;          // commitment_loss
        out[OUT_S + 2] = e;                  // codebook_loss
        out[OUT_S + 3] = perp;               // perplexity
    }
}

extern "C" void kernel_launch(void* const* d_in, const int* in_sizes, int n_in,
                              void* d_out, int out_size, void* d_ws, size_t ws_size,
                              hipStream_t stream) {
    const float* inp = (const float*)d_in[0];
    const float* cb = (const float*)d_in[1];
    float* out = (float*)d_out;
    char* ws = (char*)d_ws;
    u16* A = (u16*)(ws + A_OFF);
    u16* B = (u16*)(ws + B_OFF);
    float* cn = (float*)(ws + CN_OFF);
    u64* part1 = (u64*)(ws + PART1_OFF);
    float* part2 = (float*)(ws + PART2_OFF);
    unsigned* idx32 = (unsigned*)(ws + IDX_OFF);
    unsigned int* hist = (unsigned int*)(ws + HIST_OFF);
    int* cnt = (int*)(ws + CNT_OFF);
    int* flaglist = (int*)(ws + FLAG_OFF);
    float* losspart = (float*)(ws + LOSS_OFF);
    float* cbT = (float*)(ws + CBT_OFF);

    hipMemsetAsync(hist, 0, K_CODES * 4 + 16, stream);   // hist + cnt

    prep<<<5120, 256, 0, stream>>>(inp, cb, A, B, cn);
    transpose_cb<<<dim3(K_CODES / 64, DIM / 64), 256, 0, stream>>>(cb, cbT);
    vq_pass1<<<dim3(N_ROWS / BM, JSPLIT), 256, 0, stream>>>(A, B, cn, part1, part2);
    vq_merge<<<N_ROWS / 256, 256, 0, stream>>>(part1, part2, idx32, flaglist, cnt);
    vq_recompute<<<N_ROWS / 8, 512, 0, stream>>>(inp, cbT, cn, flaglist, cnt, idx32);
    vq_gather<<<N_ROWS / 4, 256, 0, stream>>>(inp, cb, idx32, out, losspart, hist);
    vq_finalize<<<1, 256, 0, stream>>>(hist, losspart, out);
}

// Round 8
// 402.474 us; speedup vs baseline: 7.6345x; 1.4354x over previous
//
#include <hip/hip_runtime.h>
#include <stdint.h>

typedef unsigned short u16;
typedef unsigned long long u64;

#define N_ROWS 32768
#define DIM 256
#define K_CODES 8192
#define TAU 0.3f

// workspace offsets (bytes)
#define A_OFF     0ull            // 32768*256*2 = 16777216
#define B_OFF     16777216ull     // 8192*256*2  = 4194304
#define CN_OFF    20971520ull     // 8192*4
#define PART1_OFF 21004288ull     // 32768*4*8 = 1048576
#define PART2_OFF 22052864ull     // 32768*4*4 = 524288
#define IDX_OFF   22577152ull     // 32768*4
#define HIST_OFF  22708224ull     // 8192*4
#define CNT_OFF   22740992ull     // 16 (memset together with hist)
#define FLAG_OFF  22741008ull     // 32768*4
#define LOSS_OFF  22872080ull     // 8192*4
#define CBT_OFF   23068672ull     // 256*8192*4 = 8388608 (codebook transposed)
#define GMIN2_OFF 31457280ull     // 32768*8 = 262144

// output offsets (float elements)
#define OUT_Q 0
#define OUT_T 8388608
#define OUT_S 8421376

#define BM 128
#define BN 128
#define BK 64
#define JSPLIT 4
#define RSPLIT 4     // recompute code-split

// packed sentinel: dist=+inf, idx=0xffffffff (any real (dist,idx) sorts below it)
#define PACK_INF ((((u64)0xFF800000u) << 32) | 0xFFFFFFFFull)

typedef _Float16 half8 __attribute__((ext_vector_type(8)));
typedef float floatx4 __attribute__((ext_vector_type(4)));

__device__ __forceinline__ void gload_lds16(const void* g, void* l) {
    __builtin_amdgcn_global_load_lds(
        (const __attribute__((address_space(1))) void*)g,
        (__attribute__((address_space(3))) void*)l,
        16, 0, 0);
}

__device__ __forceinline__ unsigned sortable(float v) {
    unsigned u = __float_as_uint(v);
    return (u & 0x80000000u) ? ~u : (u | 0x80000000u);
}
__device__ __forceinline__ float unsortable(unsigned u) {
    return (u & 0x80000000u) ? __uint_as_float(u & 0x7fffffffu) : __uint_as_float(~u);
}
__device__ __forceinline__ u64 shfl64x(u64 v, int m) {
    return ((u64)(unsigned)__shfl_xor((int)(v >> 32), m, 64) << 32) |
           (unsigned)__shfl_xor((int)(v & 0xffffffffu), m, 64);
}
__device__ __forceinline__ u64 u64min(u64 a, u64 b) { return a < b ? a : b; }
__device__ __forceinline__ u64 u64max(u64 a, u64 b) { return a > b ? a : b; }

// fp32 -> f16 (hi) cast for inputs and codebook; fused ||c||^2.
__global__ void prep(const float* __restrict__ inp, const float* __restrict__ cb,
                     u16* __restrict__ A, u16* __restrict__ B, float* __restrict__ cn) {
    int g = blockIdx.x * 256 + threadIdx.x;       // 40960 rows * 32 threads
    int row = g >> 5;
    int kc = (g & 31) << 3;
    bool isA = row < N_ROWS;
    const float* src = isA ? inp + (size_t)row * DIM + kc
                           : cb + (size_t)(row - N_ROWS) * DIM + kc;
    u16* dst = isA ? A + (size_t)row * DIM + kc
                   : B + (size_t)(row - N_ROWS) * DIM + kc;
    float4 x0 = *(const float4*)(src);
    float4 x1 = *(const float4*)(src + 4);
    float xs[8] = {x0.x, x0.y, x0.z, x0.w, x1.x, x1.y, x1.z, x1.w};
    half8 hv;
    float s = 0.f;
#pragma unroll
    for (int i = 0; i < 8; ++i) {
        hv[i] = (_Float16)xs[i];
        s = fmaf(xs[i], xs[i], s);
    }
    *(half8*)(dst) = hv;
    if (!isA) {
#pragma unroll
        for (int m = 1; m <= 16; m <<= 1) s += __shfl_xor(s, m, 64);
        if ((g & 31) == 0) cn[row - N_ROWS] = s;
    }
}

// LDS-tiled transpose: cbT[d][j] = cb[j][d]. 64x64 tiles.
__global__ void transpose_cb(const float* __restrict__ cb, float* __restrict__ cbT) {
    __shared__ float tile[64][65];
    const int tid = threadIdx.x;
    const int tj = blockIdx.x * 64;     // code-tile base
    const int td = blockIdx.y * 64;     // dim-tile base
    const int c = (tid & 15) * 4;
    const int r0 = tid >> 4;
#pragma unroll
    for (int p = 0; p < 4; ++p) {
        int r = p * 16 + r0;
        float4 v = *(const float4*)(cb + (size_t)(tj + r) * DIM + td + c);
        tile[r][c] = v.x; tile[r][c + 1] = v.y; tile[r][c + 2] = v.z; tile[r][c + 3] = v.w;
    }
    __syncthreads();
#pragma unroll
    for (int p = 0; p < 4; ++p) {
        int rr = p * 16 + r0;
        float4 w = {tile[c][rr], tile[c + 1][rr], tile[c + 2][rr], tile[c + 3][rr]};
        *(float4*)(cbT + (size_t)(td + rr) * K_CODES + tj + c) = w;
    }
}

// pass 1: hi*hi K=256 f16 MFMA GEMM + per-row top-2.
__launch_bounds__(256, 2)
__global__ void vq_pass1(const u16* __restrict__ A, const u16* __restrict__ B,
                         const float* __restrict__ cn,
                         u64* __restrict__ part1, float* __restrict__ part2) {
    __shared__ __align__(16) _Float16 lsA[BM * BK];
    __shared__ __align__(16) _Float16 lsB[BN * BK];
    __shared__ u64 t1buf[BM];
    __shared__ float t2buf[BM];

    const int tid = threadIdx.x;
    const int lane = tid & 63;
    const int w = tid >> 6;
    const int wm = w >> 1, wn = w & 1;
    const int l15 = lane & 15;
    const int quad = lane >> 4;
    const int xm = l15 & 7;
    const int rowBase = blockIdx.x * BM;
    const int jBase = blockIdx.y * (K_CODES / JSPLIT);

    float d1[16], d2[16];
    unsigned idxr[16];
#pragma unroll
    for (int i = 0; i < 16; ++i) {
        d1[i] = __builtin_inff(); d2[i] = __builtin_inff(); idxr[i] = 0xffffffffu;
    }

    const int str = tid >> 3;
    const int sk16 = tid & 7;

    for (int jc = 0; jc < (K_CODES / JSPLIT) / BN; ++jc) {
        const int colBase = jBase + jc * BN;
        floatx4 acc[4][4];
#pragma unroll
        for (int mi = 0; mi < 4; ++mi)
#pragma unroll
            for (int ni = 0; ni < 4; ++ni)
                acc[mi][ni] = (floatx4){0.f, 0.f, 0.f, 0.f};

#pragma unroll 1
        for (int kk = 0; kk < DIM; kk += BK) {
#pragma unroll
            for (int it = 0; it < 4; ++it) {
                int r = it * 32 + str;
                int cdat = sk16 ^ (r & 7);           // XOR-swizzled source chunk
                int ch = it * 256 + tid;
                gload_lds16(A + (size_t)(rowBase + r) * DIM + kk + cdat * 8,
                            (char*)lsA + ch * 16);
                gload_lds16(B + (size_t)(colBase + r) * DIM + kk + cdat * 8,
                            (char*)lsB + ch * 16);
            }
            __syncthreads();
#pragma unroll
            for (int s = 0; s < 2; ++s) {
                const int koff = ((s * 4 + quad) ^ xm) * 8;
                half8 af[4], bf[4];
#pragma unroll
                for (int mi = 0; mi < 4; ++mi)
                    af[mi] = *(const half8*)(lsA + (wm * 64 + mi * 16 + l15) * BK + koff);
#pragma unroll
                for (int ni = 0; ni < 4; ++ni)
                    bf[ni] = *(const half8*)(lsB + (wn * 64 + ni * 16 + l15) * BK + koff);
#pragma unroll
                for (int mi = 0; mi < 4; ++mi)
#pragma unroll
                    for (int ni = 0; ni < 4; ++ni)
                        acc[mi][ni] = __builtin_amdgcn_mfma_f32_16x16x32_f16(
                            af[mi], bf[ni], acc[mi][ni], 0, 0, 0);
            }
            __syncthreads();
        }

        // top-2 insert, 6 VALU/element; C/D layout col=lane&15, row=quad*4+reg
#pragma unroll
        for (int ni = 0; ni < 4; ++ni) {
            unsigned j = (unsigned)(colBase + wn * 64 + ni * 16 + l15);
            float cnj = cn[j];
#pragma unroll
            for (int mi = 0; mi < 4; ++mi) {
#pragma unroll
                for (int r = 0; r < 4; ++r) {
                    int tr = mi * 4 + r;
                    float val = fmaf(-2.0f, acc[mi][ni][r], cnj);
                    bool lt = val < d1[tr];
                    float sec = lt ? d1[tr] : val;
                    d2[tr] = fminf(d2[tr], sec);
                    d1[tr] = lt ? val : d1[tr];
                    idxr[tr] = lt ? j : idxr[tr];
                }
            }
        }
    }

    // pack (cold) and merge across the 16 lanes sharing each row
    u64 m1[16];
#pragma unroll
    for (int tr = 0; tr < 16; ++tr)
        m1[tr] = ((u64)sortable(d1[tr]) << 32) | idxr[tr];
#pragma unroll
    for (int m = 1; m <= 8; m <<= 1)
#pragma unroll
        for (int tr = 0; tr < 16; ++tr) {
            u64 o1 = shfl64x(m1[tr], m);
            float o2 = __shfl_xor(d2[tr], m, 64);
            u64 n1 = u64min(m1[tr], o1);
            float big = unsortable((unsigned)(u64max(m1[tr], o1) >> 32));
            d2[tr] = fminf(big, fminf(d2[tr], o2));
            m1[tr] = n1;
        }

    // merge the two column-half waves (wn=0 publishes, wn=1 merges & writes)
    if (wn == 0 && l15 == 0) {
#pragma unroll
        for (int tr = 0; tr < 16; ++tr) {
            int rl = wm * 64 + (tr >> 2) * 16 + quad * 4 + (tr & 3);
            t1buf[rl] = m1[tr]; t2buf[rl] = d2[tr];
        }
    }
    __syncthreads();
    if (wn == 1 && l15 == 0) {
#pragma unroll
        for (int tr = 0; tr < 16; ++tr) {
            int rl = wm * 64 + (tr >> 2) * 16 + quad * 4 + (tr & 3);
            u64 o1 = t1buf[rl];
            float o2 = t2buf[rl];
            u64 n1 = u64min(m1[tr], o1);
            float big = unsortable((unsigned)(u64max(m1[tr], o1) >> 32));
            float n2 = fminf(big, fminf(d2[tr], o2));
            size_t p = (size_t)(rowBase + rl) * JSPLIT + blockIdx.y;
            part1[p] = n1;
            part2[p] = n2;
        }
    }
}

// merge JSPLIT partial top-2s; emit idx + flag near-ties for exact recompute
__global__ void vq_merge(const u64* __restrict__ part1, const float* __restrict__ part2,
                         unsigned* __restrict__ idx32,
                         int* __restrict__ flaglist, int* __restrict__ cnt) {
    int row = blockIdx.x * 256 + threadIdx.x;
    u64 m1 = PACK_INF;
    float f2 = __builtin_inff();
#pragma unroll
    for (int y = 0; y < JSPLIT; ++y) {
        u64 p1 = part1[(size_t)row * JSPLIT + y];
        float p2 = part2[(size_t)row * JSPLIT + y];
        u64 n1 = u64min(m1, p1);
        float big = unsortable((unsigned)(u64max(m1, p1) >> 32));
        f2 = fminf(big, fminf(f2, p2));
        m1 = n1;
    }
    idx32[row] = (unsigned)(m1 & 0xffffffffu);
    float f1 = unsortable((unsigned)(m1 >> 32));
    if (f2 - f1 < TAU) {
        int p = atomicAdd(cnt, 1);
        flaglist[p] = row;
    }
}

// exact fp32 full-scan argmin for flagged rows, v5:
// grid (rowgroups, RSPLIT): block = 8 rows x 2048 codes (2 MB cbT chunk,
// L2-resident & shared across co-resident blocks). 512 thr, thread owns 4
// consecutive codes; cv software-pipelined (load d+1 before computing d).
// Cross-split merge via global atomicMin on packed (sortable-dist|idx).
__global__ void vq_recompute(const float* __restrict__ inp, const float* __restrict__ cbT,
                             const float* __restrict__ cn, const int* __restrict__ flaglist,
                             const int* __restrict__ cnt, u64* __restrict__ gmin2) {
    __shared__ float xsT[DIM][8];
    __shared__ u64 wred[8][8];
    const int tid = threadIdx.x;
    const int w = tid >> 6, lane = tid & 63;
    const int n = *cnt;
    const int base = blockIdx.x * 8;
    if (base >= n) return;

    // stage 8 rows transposed: wave w loads row (base+w), lane covers 4 dims
    {
        int li = base + w;
        int row = flaglist[li < n ? li : (n - 1)];
        float4 a = ((const float4*)(inp + (size_t)row * DIM))[lane];
        int d0 = lane * 4;
        xsT[d0 + 0][w] = a.x; xsT[d0 + 1][w] = a.y;
        xsT[d0 + 2][w] = a.z; xsT[d0 + 3][w] = a.w;
    }
    __syncthreads();

    const int cbase = blockIdx.y * (K_CODES / RSPLIT) + tid * 4;  // this thread's 4 codes
    float4 acc[8];
#pragma unroll
    for (int r = 0; r < 8; ++r) acc[r] = (float4){0.f, 0.f, 0.f, 0.f};

    float4 cv = *(const float4*)(cbT + cbase);      // d = 0
#pragma unroll 4
    for (int d = 0; d < DIM - 1; ++d) {
        float4 nx = *(const float4*)(cbT + (size_t)(d + 1) * K_CODES + cbase);
        float4 xa = *(const float4*)&xsT[d][0];
        float4 xb = *(const float4*)&xsT[d][4];
        float xv[8] = {xa.x, xa.y, xa.z, xa.w, xb.x, xb.y, xb.z, xb.w};
#pragma unroll
        for (int r = 0; r < 8; ++r) {
            acc[r].x = fmaf(xv[r], cv.x, acc[r].x);
            acc[r].y = fmaf(xv[r], cv.y, acc[r].y);
            acc[r].z = fmaf(xv[r], cv.z, acc[r].z);
            acc[r].w = fmaf(xv[r], cv.w, acc[r].w);
        }
        cv = nx;
    }
    {
        const int d = DIM - 1;
        float4 xa = *(const float4*)&xsT[d][0];
        float4 xb = *(const float4*)&xsT[d][4];
        float xv[8] = {xa.x, xa.y, xa.z, xa.w, xb.x, xb.y, xb.z, xb.w};
#pragma unroll
        for (int r = 0; r < 8; ++r) {
            acc[r].x = fmaf(xv[r], cv.x, acc[r].x);
            acc[r].y = fmaf(xv[r], cv.y, acc[r].y);
            acc[r].z = fmaf(xv[r], cv.z, acc[r].z);
            acc[r].w = fmaf(xv[r], cv.w, acc[r].w);
        }
    }

    u64 best[8];
    float4 cn4 = *(const float4*)(cn + cbase);
#pragma unroll
    for (int r = 0; r < 8; ++r) {
        float d0 = cn4.x - 2.0f * acc[r].x;
        float d1 = cn4.y - 2.0f * acc[r].y;
        float d2 = cn4.z - 2.0f * acc[r].z;
        float d3 = cn4.w - 2.0f * acc[r].w;
        u64 b = ((u64)sortable(d0) << 32) | (unsigned)(cbase + 0);
        b = u64min(b, ((u64)sortable(d1) << 32) | (unsigned)(cbase + 1));
        b = u64min(b, ((u64)sortable(d2) << 32) | (unsigned)(cbase + 2));
        b = u64min(b, ((u64)sortable(d3) << 32) | (unsigned)(cbase + 3));
        best[r] = b;
    }

    // reduce across 64 lanes, then across 8 waves, then atomicMin to global
#pragma unroll
    for (int m = 1; m <= 32; m <<= 1)
#pragma unroll
        for (int r = 0; r < 8; ++r) best[r] = u64min(best[r], shfl64x(best[r], m));
    if (lane < 8) wred[w][lane] = best[lane];
    __syncthreads();
    if (tid < 8 && base + tid < n) {
        u64 b = wred[0][tid];
#pragma unroll
        for (int ww = 1; ww < 8; ++ww) b = u64min(b, wred[ww][tid]);
        atomicMin(&gmin2[flaglist[base + tid]], b);
    }
}

// write recomputed indices back into idx32
__global__ void vq_writeback(const u64* __restrict__ gmin2, const int* __restrict__ flaglist,
                             const int* __restrict__ cnt, unsigned* __restrict__ idx32) {
    int i = blockIdx.x * 256 + threadIdx.x;
    if (i < *cnt) {
        int row = flaglist[i];
        idx32[row] = (unsigned)(gmin2[row] & 0xffffffffull);
    }
}

// gather codebook rows, write quantized + tokens, per-block loss partial, histogram
__global__ void vq_gather(const float* __restrict__ inp, const float* __restrict__ cb,
                          const unsigned* __restrict__ idx32, float* __restrict__ out,
                          float* __restrict__ losspart, unsigned int* __restrict__ hist) {
    __shared__ float red[4];
    int w = threadIdx.x >> 6, lane = threadIdx.x & 63;
    int i = blockIdx.x * 4 + w;
    unsigned idx = idx32[i];
    float4 c = ((const float4*)(cb + (size_t)idx * DIM))[lane];
    float4 x = ((const float4*)(inp + (size_t)i * DIM))[lane];
    ((float4*)(out + OUT_Q))[(size_t)i * 64 + lane] = c;
    float dx = c.x - x.x, dy = c.y - x.y, dz = c.z - x.z, dw = c.w - x.w;
    float s = dx * dx + dy * dy + dz * dz + dw * dw;
#pragma unroll
    for (int m = 32; m; m >>= 1) s += __shfl_xor(s, m, 64);
    if (lane == 0) {
        out[OUT_T + i] = (float)idx;
        red[w] = s;
        atomicAdd(&hist[idx], 1u);
    }
    __syncthreads();
    if (threadIdx.x == 0)
        losspart[blockIdx.x] = red[0] + red[1] + red[2] + red[3];
}

__global__ void vq_finalize(const unsigned int* __restrict__ hist,
                            const float* __restrict__ losspart, float* __restrict__ out) {
    __shared__ float redp[256], redl[256];
    int tid = threadIdx.x;
    float sp = 0.f, sl = 0.f;
    for (int k = tid; k < K_CODES; k += 256) {
        float p = (float)hist[k] * (1.0f / (float)N_ROWS);
        sp += p * logf(p + 1e-10f);
        sl += losspart[k];
    }
    redp[tid] = sp; redl[tid] = sl;
    __syncthreads();
    for (int st = 128; st; st >>= 1) {
        if (tid < st) { redp[tid] += redp[tid + st]; redl[tid] += redl[tid + st]; }
        __syncthreads();
    }
    if (tid == 0) {
        float perp = expf(-redp[0]);
        float e = redl[0] / 8388608.0f;      // mean((q - x)^2)
        out[OUT_S + 0] = 1.25f * e;          // vq_loss
        out[OUT_S + 1] = 0.25f * e;          // commitment_loss
        out[OUT_S + 2] = e;                  // codebook_loss
        out[OUT_S + 3] = perp;               // perplexity
    }
}

extern "C" void kernel_launch(void* const* d_in, const int* in_sizes, int n_in,
                              void* d_out, int out_size, void* d_ws, size_t ws_size,
                              hipStream_t stream) {
    const float* inp = (const float*)d_in[0];
    const float* cb = (const float*)d_in[1];
    float* out = (float*)d_out;
    char* ws = (char*)d_ws;
    u16* A = (u16*)(ws + A_OFF);
    u16* B = (u16*)(ws + B_OFF);
    float* cn = (float*)(ws + CN_OFF);
    u64* part1 = (u64*)(ws + PART1_OFF);
    float* part2 = (float*)(ws + PART2_OFF);
    unsigned* idx32 = (unsigned*)(ws + IDX_OFF);
    unsigned int* hist = (unsigned int*)(ws + HIST_OFF);
    int* cnt = (int*)(ws + CNT_OFF);
    int* flaglist = (int*)(ws + FLAG_OFF);
    float* losspart = (float*)(ws + LOSS_OFF);
    float* cbT = (float*)(ws + CBT_OFF);
    u64* gmin2 = (u64*)(ws + GMIN2_OFF);

    hipMemsetAsync(hist, 0, K_CODES * 4 + 16, stream);   // hist + cnt
    hipMemsetAsync(gmin2, 0xFF, N_ROWS * 8, stream);

    prep<<<5120, 256, 0, stream>>>(inp, cb, A, B, cn);
    transpose_cb<<<dim3(K_CODES / 64, DIM / 64), 256, 0, stream>>>(cb, cbT);
    vq_pass1<<<dim3(N_ROWS / BM, JSPLIT), 256, 0, stream>>>(A, B, cn, part1, part2);
    vq_merge<<<N_ROWS / 256, 256, 0, stream>>>(part1, part2, idx32, flaglist, cnt);
    vq_recompute<<<dim3(N_ROWS / 8, RSPLIT), 512, 0, stream>>>(inp, cbT, cn, flaglist, cnt, gmin2);
    vq_writeback<<<N_ROWS / 256, 256, 0, stream>>>(gmin2, flaglist, cnt, idx32);
    vq_gather<<<N_ROWS / 4, 256, 0, stream>>>(inp, cb, idx32, out, losspart, hist);
    vq_finalize<<<1, 256, 0, stream>>>(hist, losspart, out);
}